// Round 7
// baseline (478.379 us; speedup 1.0000x reference)
//
#include <hip/hip_runtime.h>
#include <stdint.h>

#define N_NODES 50000
#define N_EDGES 600000
#define NCLS    47
#define SCAN_TPB 512
#define SCAN_BLOCKS ((N_NODES + SCAN_TPB - 1) / SCAN_TPB)   // 98

typedef __attribute__((ext_vector_type(8))) short short8;
typedef __attribute__((ext_vector_type(4))) float f32x4;

static __device__ __forceinline__ float bf2f(uint16_t h) {
    union { uint32_t u; float f; } c; c.u = ((uint32_t)h) << 16; return c.f;
}
static __device__ __forceinline__ float bf2fs(short h) { return bf2f((uint16_t)h); }
static __device__ __forceinline__ uint16_t f2bf(float f) {
    union { float f; uint32_t u; } c; c.f = f;
    uint32_t u = c.u;
    return (uint16_t)((u + 0x7fffu + ((u >> 16) & 1u)) >> 16); // RNE
}

// ---------------- split f32 matrix -> bf16 hi + bf16 lo arrays (x only)
__global__ __launch_bounds__(256) void k_split(const float4* __restrict__ x,
                                               ushort4* __restrict__ xh,
                                               ushort4* __restrict__ xl) {
    int i = blockIdx.x * 256 + threadIdx.x;   // 1.6M float4s
    float4 v = x[i];
    ushort4 h, l;
    h.x = f2bf(v.x); l.x = f2bf(v.x - bf2f(h.x));
    h.y = f2bf(v.y); l.y = f2bf(v.y - bf2f(h.y));
    h.z = f2bf(v.z); l.z = f2bf(v.z - bf2f(h.z));
    h.w = f2bf(v.w); l.w = f2bf(v.w - bf2f(h.w));
    xh[i] = h;
    xl[i] = l;
}

// ---------- edge_index canonicalize (int64-or-int32 -> int32) + degree count
__global__ __launch_bounds__(256) void k_cvt_idx(const int* __restrict__ ei,
                                                 int* __restrict__ src,
                                                 int* __restrict__ dst,
                                                 int* __restrict__ deg) {
    __shared__ int is64;
    {
        int lane = threadIdx.x;
        if (lane < 64) {
            int f = ei[2 * lane + 1] | ei[2 * lane + 129]; // 128 hi-words if int64
            unsigned long long m = __ballot(f != 0);
            if (lane == 0) is64 = (m == 0ULL) ? 1 : 0;
        }
        __syncthreads();
    }
    int e = blockIdx.x * 256 + threadIdx.x;
    if (e < N_EDGES) {
        int s, d;
        if (is64) { s = ei[2 * e]; d = ei[2 * (N_EDGES + e)]; }
        else      { s = ei[e];     d = ei[N_EDGES + e]; }
        s = min(max(s, 0), N_NODES - 1);
        d = min(max(d, 0), N_NODES - 1);
        src[e] = s;
        dst[e] = d;
        atomicAdd(&deg[d], 1);
    }
}

// ------------------------------------------- scan stage 1: per-block partials
__global__ __launch_bounds__(SCAN_TPB) void k_scan1(const int* __restrict__ deg,
                                                    int* __restrict__ partial) {
    int t = blockIdx.x * SCAN_TPB + threadIdx.x;
    int v = (t < N_NODES) ? deg[t] : 0;
#pragma unroll
    for (int o = 1; o < 64; o <<= 1) v += __shfl_xor(v, o);
    __shared__ int ws[SCAN_TPB / 64];
    int lane = threadIdx.x & 63, w = threadIdx.x >> 6;
    if (lane == 0) ws[w] = v;
    __syncthreads();
    if (threadIdx.x == 0) {
        int s = 0;
#pragma unroll
        for (int i = 0; i < SCAN_TPB / 64; ++i) s += ws[i];
        partial[blockIdx.x] = s;
    }
}

// ---------------------------- scan stage 2: exclusive scan of 98 partials
__global__ __launch_bounds__(128) void k_scan2(int* __restrict__ partial) {
    __shared__ int sh[128];
    int t = threadIdx.x;
    int v = (t < SCAN_BLOCKS) ? partial[t] : 0;
    sh[t] = v;
    __syncthreads();
    for (int o = 1; o < 128; o <<= 1) {
        int u = (t >= o) ? sh[t - o] : 0;
        __syncthreads();
        sh[t] += u;
        __syncthreads();
    }
    if (t < SCAN_BLOCKS) partial[t] = sh[t] - v; // exclusive
}

// --------------- scan stage 3: block-local exclusive scan + offset, emit CSR
__global__ __launch_bounds__(SCAN_TPB) void k_scan3(const int* __restrict__ deg,
                                                    const int* __restrict__ partial,
                                                    int* __restrict__ row_start,
                                                    int* __restrict__ fill,
                                                    float* __restrict__ inv_deg) {
    int tb = threadIdx.x;
    int t = blockIdx.x * SCAN_TPB + tb;
    int v = (t < N_NODES) ? deg[t] : 0;
    int lane = tb & 63, w = tb >> 6;
    int inc = v;
#pragma unroll
    for (int o = 1; o < 64; o <<= 1) {
        int u = __shfl_up(inc, o);
        if (lane >= o) inc += u;
    }
    __shared__ int wsum[SCAN_TPB / 64];
    if (lane == 63) wsum[w] = inc;
    __syncthreads();
    int woff = 0;
    for (int i = 0; i < w; ++i) woff += wsum[i];
    int excl = partial[blockIdx.x] + woff + (inc - v);
    if (t < N_NODES) {
        row_start[t] = excl;
        fill[t] = excl;
        inv_deg[t] = 1.0f / (float)(v > 0 ? v : 1);
    }
}

// ---------------------------------------------------------------- bucket fill
__global__ __launch_bounds__(256) void k_fill(const int* __restrict__ src,
                                              const int* __restrict__ dst,
                                              int* __restrict__ fill,
                                              int* __restrict__ elist) {
    int e = blockIdx.x * 256 + threadIdx.x;
    if (e < N_EDGES) {
        int pos = atomicAdd(&fill[dst[e]], 1);
        elist[pos] = src[e];
    }
}

// -------- mean aggregation, hi/lo bf16 in & out (half-wave/node; lanes 0-15
// stream the hi array, lanes 16-31 the lo array; combine via shfl_xor(16))
__global__ __launch_bounds__(256) void k_agg(const uint16_t* __restrict__ hm_h,
                                             const uint16_t* __restrict__ hm_l,
                                             const int* __restrict__ row_start,
                                             const int* __restrict__ degv,
                                             const float* __restrict__ inv_deg,
                                             const int* __restrict__ elist,
                                             uint16_t* __restrict__ agg_h,
                                             uint16_t* __restrict__ agg_l) {
    int l32 = threadIdx.x & 31;
    int node = blockIdx.x * 8 + (threadIdx.x >> 5);
    if (node >= N_NODES) return;
    int rs = row_start[node];
    int d = degv[node];
    const uint16_t* base = (l32 < 16) ? hm_h : hm_l;
    int j = (l32 & 15) * 8;                 // element offset of this lane's chunk
    float a[8];
#pragma unroll
    for (int k = 0; k < 8; ++k) a[k] = 0.f;
    int i = 0;
    for (; i + 4 <= d; i += 4) {
        int s0 = elist[rs + i];
        int s1 = elist[rs + i + 1];
        int s2 = elist[rs + i + 2];
        int s3 = elist[rs + i + 3];
        short8 w0 = *(const short8*)&base[(size_t)s0 * 128 + j];
        short8 w1 = *(const short8*)&base[(size_t)s1 * 128 + j];
        short8 w2 = *(const short8*)&base[(size_t)s2 * 128 + j];
        short8 w3 = *(const short8*)&base[(size_t)s3 * 128 + j];
#pragma unroll
        for (int k = 0; k < 8; ++k)
            a[k] += (bf2fs(w0[k]) + bf2fs(w1[k])) + (bf2fs(w2[k]) + bf2fs(w3[k]));
    }
    for (; i < d; ++i) {
        int s = elist[rs + i];
        short8 w = *(const short8*)&base[(size_t)s * 128 + j];
#pragma unroll
        for (int k = 0; k < 8; ++k) a[k] += bf2fs(w[k]);
    }
    float sc = inv_deg[node];
    short8 outv;
#pragma unroll
    for (int k = 0; k < 8; ++k) {
        float v = (a[k] + __shfl_xor(a[k], 16)) * sc;
        uint16_t h = f2bf(v);
        outv[k] = (l32 < 16) ? (short)h : (short)f2bf(v - bf2f(h));
    }
    uint16_t* dstp = (l32 < 16) ? agg_h : agg_l;
    *(short8*)&dstp[(size_t)node * 128 + j] = outv;
}

// -------------- weight prep: transpose W[k][col] -> img[col][k], bf16 hi + lo
// 64 blocks per matrix (6 matrices, grid=384)
__global__ __launch_bounds__(256) void k_prepw(const float* Wl0, const float* Wr0,
                                               const float* Wl1, const float* Wr1,
                                               const float* Wl2, const float* Wr2,
                                               uint16_t* __restrict__ img) {
    int b = blockIdx.x >> 6;
    int sub = blockIdx.x & 63;
    const float* W; int ncol, npad; uint16_t* o;
    switch (b) {
        case 0: W = Wl0; ncol = 128; npad = 128; o = img;           break;
        case 1: W = Wr0; ncol = 128; npad = 128; o = img + 32768;   break;
        case 2: W = Wl1; ncol = 128; npad = 128; o = img + 65536;   break;
        case 3: W = Wr1; ncol = 128; npad = 128; o = img + 98304;   break;
        case 4: W = Wl2; ncol = 47;  npad = 48;  o = img + 131072;  break;
        default:W = Wr2; ncol = 47;  npad = 48;  o = img + 143360;  break;
    }
    int elems = npad * 128;
    int i = sub * 256 + threadIdx.x;
    if (i < elems) {
        int col = i % npad, k = i / npad;
        float v = (col < ncol) ? W[k * ncol + col] : 0.f;
        uint16_t h = f2bf(v);
        uint16_t l = f2bf(v - bf2f(h));
        int idx = col * 128 + k;
        o[idx] = h;
        o[idx + elems] = l;
    }
}

// ------- GEMM layers 0/1: out(hi/lo) = relu(A1@Wl + A2@Wr + b)
// 8 waves; wave wv owns col-tile wv with its W fragments REGISTER-RESIDENT
// (16 short8 = 64 VGPR). Strip-mines 64 rows in 4 chunks of 16.
// Inner loop: A loads + MFMA only — zero W traffic.
__global__ __launch_bounds__(512) void k_gemm(const uint16_t* __restrict__ A1h,
                                              const uint16_t* __restrict__ A1l,
                                              const uint16_t* __restrict__ A2h,
                                              const uint16_t* __restrict__ A2l,
                                              const uint16_t* __restrict__ wl,
                                              const uint16_t* __restrict__ wr,
                                              const float* __restrict__ bias,
                                              uint16_t* __restrict__ outh,
                                              uint16_t* __restrict__ outl) {
    int tid = threadIdx.x;
    int lane = tid & 63, wv = tid >> 6;      // wv = col-tile 0..7
    int li = lane & 15, g4 = lane >> 4;
    int col = wv * 16 + li;

    // hoist W fragments for this col-tile
    short8 WH[2][4], WLo[2][4];
#pragma unroll
    for (int arr = 0; arr < 2; ++arr) {
        const uint16_t* W = arr ? wr : wl;
#pragma unroll
        for (int s = 0; s < 4; ++s) {
            const uint16_t* p = &W[col * 128 + s * 32 + g4 * 8];
            WH[arr][s]  = *(const short8*)p;
            WLo[arr][s] = *(const short8*)(p + 16384);
        }
    }
    float bv = bias[col];

    int base = blockIdx.x * 64;
#pragma unroll
    for (int c = 0; c < 4; ++c) {
        int row0 = base + c * 16;
        int r = min(row0 + li, N_NODES - 1);
        f32x4 acc = (f32x4){0.f, 0.f, 0.f, 0.f};
#pragma unroll
        for (int arr = 0; arr < 2; ++arr) {
            const uint16_t* Ah = arr ? A2h : A1h;
            const uint16_t* Al = arr ? A2l : A1l;
#pragma unroll
            for (int s = 0; s < 4; ++s) {
                int ko = s * 32 + g4 * 8;
                short8 ah = *(const short8*)&Ah[(size_t)r * 128 + ko];
                short8 al = *(const short8*)&Al[(size_t)r * 128 + ko];
                acc = __builtin_amdgcn_mfma_f32_16x16x32_bf16(ah, WH[arr][s], acc, 0, 0, 0);
                acc = __builtin_amdgcn_mfma_f32_16x16x32_bf16(al, WH[arr][s], acc, 0, 0, 0);
                acc = __builtin_amdgcn_mfma_f32_16x16x32_bf16(ah, WLo[arr][s], acc, 0, 0, 0);
            }
        }
        // epilogue: bias + relu, split hi/lo.  D layout: col=li, row=g4*4+rr
        int rowb = row0 + g4 * 4;
#pragma unroll
        for (int rr = 0; rr < 4; ++rr) {
            int row = rowb + rr;
            if (row < N_NODES) {
                float v = fmaxf(acc[rr] + bv, 0.f);
                uint16_t h = f2bf(v);
                outh[(size_t)row * 128 + col] = h;
                outl[(size_t)row * 128 + col] = f2bf(v - bf2f(h));
            }
        }
    }
}

// -------- layer 2 GEMM fused with L2-normalize + log_softmax, out f32[N][47]
__global__ __launch_bounds__(256) void k_gemm2(const uint16_t* __restrict__ A1h,
                                               const uint16_t* __restrict__ A1l,
                                               const uint16_t* __restrict__ A2h,
                                               const uint16_t* __restrict__ A2l,
                                               const uint16_t* __restrict__ wl,
                                               const uint16_t* __restrict__ wr,
                                               const float* __restrict__ bias,
                                               float* __restrict__ out) {
    int tid = threadIdx.x;
    int lane = tid & 63, wv = tid >> 6;
    int li = lane & 15, g4 = lane >> 4;
    int mrow = blockIdx.x * 64 + wv * 16 + li;
    int r = min(mrow, N_NODES - 1);

    f32x4 acc[3];
#pragma unroll
    for (int t = 0; t < 3; ++t) acc[t] = (f32x4){0.f, 0.f, 0.f, 0.f};

#pragma unroll
    for (int arr = 0; arr < 2; ++arr) {
        const uint16_t* Ah = arr ? A2h : A1h;
        const uint16_t* Al = arr ? A2l : A1l;
        const uint16_t* W  = arr ? wr : wl;
#pragma unroll
        for (int s = 0; s < 4; ++s) {
            int ko = s * 32 + g4 * 8;
            short8 ah = *(const short8*)&Ah[(size_t)r * 128 + ko];
            short8 al = *(const short8*)&Al[(size_t)r * 128 + ko];
#pragma unroll
            for (int t = 0; t < 3; ++t) {
                const uint16_t* p = &W[(t * 16 + li) * 128 + ko];
                short8 bh = *(const short8*)p;
                short8 bl = *(const short8*)(p + 6144);
                acc[t] = __builtin_amdgcn_mfma_f32_16x16x32_bf16(ah, bh, acc[t], 0, 0, 0);
                acc[t] = __builtin_amdgcn_mfma_f32_16x16x32_bf16(al, bh, acc[t], 0, 0, 0);
                acc[t] = __builtin_amdgcn_mfma_f32_16x16x32_bf16(ah, bl, acc[t], 0, 0, 0);
            }
        }
    }

    float b0 = bias[li];
    float b1 = bias[16 + li];
    bool v2ok = (li < 15);
    float b2 = v2ok ? bias[32 + li] : 0.f;

    int rowbase = blockIdx.x * 64 + wv * 16 + g4 * 4;
#pragma unroll
    for (int rr = 0; rr < 4; ++rr) {
        int row = rowbase + rr;
        float v0 = acc[0][rr] + b0;
        float v1 = acc[1][rr] + b1;
        float v2 = v2ok ? (acc[2][rr] + b2) : 0.f;
        float ss = v0 * v0 + v1 * v1 + v2 * v2;
        ss += __shfl_xor(ss, 1);
        ss += __shfl_xor(ss, 2);
        ss += __shfl_xor(ss, 4);
        ss += __shfl_xor(ss, 8);
        float inv = 1.f / fmaxf(sqrtf(ss), 1e-12f);
        v0 *= inv; v1 *= inv; v2 *= inv;
        float mx = fmaxf(v0, v1);
        if (v2ok) mx = fmaxf(mx, v2);
        mx = fmaxf(mx, __shfl_xor(mx, 1));
        mx = fmaxf(mx, __shfl_xor(mx, 2));
        mx = fmaxf(mx, __shfl_xor(mx, 4));
        mx = fmaxf(mx, __shfl_xor(mx, 8));
        float se = expf(v0 - mx) + expf(v1 - mx) + (v2ok ? expf(v2 - mx) : 0.f);
        se += __shfl_xor(se, 1);
        se += __shfl_xor(se, 2);
        se += __shfl_xor(se, 4);
        se += __shfl_xor(se, 8);
        float lse = logf(se);
        if (row < N_NODES) {
            size_t ob = (size_t)row * NCLS;
            out[ob + li]      = v0 - mx - lse;
            out[ob + 16 + li] = v1 - mx - lse;
            if (v2ok) out[ob + 32 + li] = v2 - mx - lse;
        }
    }
}

// ---------------------------------------------------------------------------
extern "C" void kernel_launch(void* const* d_in, const int* in_sizes, int n_in,
                              void* d_out, int out_size, void* d_ws, size_t ws_size,
                              hipStream_t stream) {
    const float* x   = (const float*)d_in[0];
    const int*   ei  = (const int*)d_in[1];
    const float* Wl0 = (const float*)d_in[2];
    const float* bl0 = (const float*)d_in[3];
    const float* Wr0 = (const float*)d_in[4];
    const float* Wl1 = (const float*)d_in[5];
    const float* bl1 = (const float*)d_in[6];
    const float* Wr1 = (const float*)d_in[7];
    const float* Wl2 = (const float*)d_in[8];
    const float* bl2 = (const float*)d_in[9];
    const float* Wr2 = (const float*)d_in[10];
    float* out = (float*)d_out;

    char* ws = (char*)d_ws;
    size_t cur = 0;
    auto alloc = [&](size_t bytes) {
        char* p = ws + cur;
        cur += (bytes + 255) & ~(size_t)255;
        return p;
    };
    const size_t MATB = (size_t)N_NODES * 128 * 2;   // bf16 matrix bytes
    int*      deg       = (int*)alloc(N_NODES * 4);
    int*      row_start = (int*)alloc(N_NODES * 4);
    int*      fill      = (int*)alloc(N_NODES * 4);
    float*    inv_deg   = (float*)alloc(N_NODES * 4);
    int*      partial   = (int*)alloc(SCAN_BLOCKS * 4);
    int*      src       = (int*)alloc(N_EDGES * 4);
    int*      dst       = (int*)alloc(N_EDGES * 4);
    int*      elist     = (int*)alloc(N_EDGES * 4);
    uint16_t* wimg      = (uint16_t*)alloc(155648 * 2);
    uint16_t* xh        = (uint16_t*)alloc(MATB);
    uint16_t* xl        = (uint16_t*)alloc(MATB);
    uint16_t* Ah        = (uint16_t*)alloc(MATB);
    uint16_t* Al        = (uint16_t*)alloc(MATB);
    uint16_t* Bh        = (uint16_t*)alloc(MATB);
    uint16_t* Bl        = (uint16_t*)alloc(MATB);
    uint16_t* Ch        = (uint16_t*)alloc(MATB);
    uint16_t* Cl        = (uint16_t*)alloc(MATB);

    hipMemsetAsync(deg, 0, N_NODES * 4, stream);
    k_prepw<<<384, 256, 0, stream>>>(Wl0, Wr0, Wl1, Wr1, Wl2, Wr2, wimg);
    k_split<<<(N_NODES * 128 / 4) / 256, 256, 0, stream>>>((const float4*)x,
                                                           (ushort4*)xh, (ushort4*)xl);

    int egrid = (N_EDGES + 255) / 256;
    k_cvt_idx<<<egrid, 256, 0, stream>>>(ei, src, dst, deg);
    k_scan1<<<SCAN_BLOCKS, SCAN_TPB, 0, stream>>>(deg, partial);
    k_scan2<<<1, 128, 0, stream>>>(partial);
    k_scan3<<<SCAN_BLOCKS, SCAN_TPB, 0, stream>>>(deg, partial, row_start, fill, inv_deg);
    k_fill<<<egrid, 256, 0, stream>>>(src, dst, fill, elist);

    int agrid = (N_NODES + 7) / 8;           // 6250
    int ggrid = (N_NODES + 63) / 64;         // 782

    // layer 0
    k_agg<<<agrid, 256, 0, stream>>>(xh, xl, row_start, deg, inv_deg, elist, Ah, Al);
    k_gemm<<<ggrid, 512, 0, stream>>>(Ah, Al, xh, xl, wimg, wimg + 32768, bl0, Bh, Bl);
    // layer 1
    k_agg<<<agrid, 256, 0, stream>>>(Bh, Bl, row_start, deg, inv_deg, elist, Ah, Al);
    k_gemm<<<ggrid, 512, 0, stream>>>(Ah, Al, Bh, Bl, wimg + 65536, wimg + 98304, bl1, Ch, Cl);
    // layer 2 (fused normalize + log_softmax)
    k_agg<<<agrid, 256, 0, stream>>>(Ch, Cl, row_start, deg, inv_deg, elist, Ah, Al);
    k_gemm2<<<ggrid, 256, 0, stream>>>(Ah, Al, Ch, Cl, wimg + 131072, wimg + 143360, bl2, out);
}

// Round 8
// 431.604 us; speedup vs baseline: 1.1084x; 1.1084x over previous
//
#include <hip/hip_runtime.h>
#include <stdint.h>

#define N_NODES 50000
#define N_EDGES 600000
#define NCLS    47
#define SCAN_TPB 512
#define SCAN_BLOCKS ((N_NODES + SCAN_TPB - 1) / SCAN_TPB)   // 98

typedef __attribute__((ext_vector_type(8))) short short8;
typedef __attribute__((ext_vector_type(4))) float f32x4;

static __device__ __forceinline__ float bf2f(uint16_t h) {
    union { uint32_t u; float f; } c; c.u = ((uint32_t)h) << 16; return c.f;
}
static __device__ __forceinline__ float bf2fs(short h) { return bf2f((uint16_t)h); }
static __device__ __forceinline__ uint16_t f2bf(float f) {
    union { float f; uint32_t u; } c; c.f = f;
    uint32_t u = c.u;
    return (uint16_t)((u + 0x7fffu + ((u >> 16) & 1u)) >> 16); // RNE
}

// ---------------- split f32 matrix -> bf16 hi + bf16 lo arrays (x only)
__global__ __launch_bounds__(256) void k_split(const float4* __restrict__ x,
                                               ushort4* __restrict__ xh,
                                               ushort4* __restrict__ xl) {
    int i = blockIdx.x * 256 + threadIdx.x;   // 1.6M float4s
    float4 v = x[i];
    ushort4 h, l;
    h.x = f2bf(v.x); l.x = f2bf(v.x - bf2f(h.x));
    h.y = f2bf(v.y); l.y = f2bf(v.y - bf2f(h.y));
    h.z = f2bf(v.z); l.z = f2bf(v.z - bf2f(h.z));
    h.w = f2bf(v.w); l.w = f2bf(v.w - bf2f(h.w));
    xh[i] = h;
    xl[i] = l;
}

// ---------- edge_index canonicalize (int64-or-int32 -> int32) + degree count
__global__ __launch_bounds__(256) void k_cvt_idx(const int* __restrict__ ei,
                                                 int* __restrict__ src,
                                                 int* __restrict__ dst,
                                                 int* __restrict__ deg) {
    __shared__ int is64;
    {
        int lane = threadIdx.x;
        if (lane < 64) {
            int f = ei[2 * lane + 1] | ei[2 * lane + 129]; // 128 hi-words if int64
            unsigned long long m = __ballot(f != 0);
            if (lane == 0) is64 = (m == 0ULL) ? 1 : 0;
        }
        __syncthreads();
    }
    int e = blockIdx.x * 256 + threadIdx.x;
    if (e < N_EDGES) {
        int s, d;
        if (is64) { s = ei[2 * e]; d = ei[2 * (N_EDGES + e)]; }
        else      { s = ei[e];     d = ei[N_EDGES + e]; }
        s = min(max(s, 0), N_NODES - 1);
        d = min(max(d, 0), N_NODES - 1);
        src[e] = s;
        dst[e] = d;
        atomicAdd(&deg[d], 1);
    }
}

// ------------------------------------------- scan stage 1: per-block partials
__global__ __launch_bounds__(SCAN_TPB) void k_scan1(const int* __restrict__ deg,
                                                    int* __restrict__ partial) {
    int t = blockIdx.x * SCAN_TPB + threadIdx.x;
    int v = (t < N_NODES) ? deg[t] : 0;
#pragma unroll
    for (int o = 1; o < 64; o <<= 1) v += __shfl_xor(v, o);
    __shared__ int ws[SCAN_TPB / 64];
    int lane = threadIdx.x & 63, w = threadIdx.x >> 6;
    if (lane == 0) ws[w] = v;
    __syncthreads();
    if (threadIdx.x == 0) {
        int s = 0;
#pragma unroll
        for (int i = 0; i < SCAN_TPB / 64; ++i) s += ws[i];
        partial[blockIdx.x] = s;
    }
}

// ---------------------------- scan stage 2: exclusive scan of 98 partials
__global__ __launch_bounds__(128) void k_scan2(int* __restrict__ partial) {
    __shared__ int sh[128];
    int t = threadIdx.x;
    int v = (t < SCAN_BLOCKS) ? partial[t] : 0;
    sh[t] = v;
    __syncthreads();
    for (int o = 1; o < 128; o <<= 1) {
        int u = (t >= o) ? sh[t - o] : 0;
        __syncthreads();
        sh[t] += u;
        __syncthreads();
    }
    if (t < SCAN_BLOCKS) partial[t] = sh[t] - v; // exclusive
}

// --------------- scan stage 3: block-local exclusive scan + offset, emit CSR
__global__ __launch_bounds__(SCAN_TPB) void k_scan3(const int* __restrict__ deg,
                                                    const int* __restrict__ partial,
                                                    int* __restrict__ row_start,
                                                    int* __restrict__ fill,
                                                    float* __restrict__ inv_deg) {
    int tb = threadIdx.x;
    int t = blockIdx.x * SCAN_TPB + tb;
    int v = (t < N_NODES) ? deg[t] : 0;
    int lane = tb & 63, w = tb >> 6;
    int inc = v;
#pragma unroll
    for (int o = 1; o < 64; o <<= 1) {
        int u = __shfl_up(inc, o);
        if (lane >= o) inc += u;
    }
    __shared__ int wsum[SCAN_TPB / 64];
    if (lane == 63) wsum[w] = inc;
    __syncthreads();
    int woff = 0;
    for (int i = 0; i < w; ++i) woff += wsum[i];
    int excl = partial[blockIdx.x] + woff + (inc - v);
    if (t < N_NODES) {
        row_start[t] = excl;
        fill[t] = excl;
        inv_deg[t] = 1.0f / (float)(v > 0 ? v : 1);
    }
}

// ---------------------------------------------------------------- bucket fill
__global__ __launch_bounds__(256) void k_fill(const int* __restrict__ src,
                                              const int* __restrict__ dst,
                                              int* __restrict__ fill,
                                              int* __restrict__ elist) {
    int e = blockIdx.x * 256 + threadIdx.x;
    if (e < N_EDGES) {
        int pos = atomicAdd(&fill[dst[e]], 1);
        elist[pos] = src[e];
    }
}

// -------- mean aggregation, hi/lo bf16 in & out (half-wave/node; lanes 0-15
// stream the hi array, lanes 16-31 the lo array; combine via shfl_xor(16))
__global__ __launch_bounds__(256) void k_agg(const uint16_t* __restrict__ hm_h,
                                             const uint16_t* __restrict__ hm_l,
                                             const int* __restrict__ row_start,
                                             const int* __restrict__ degv,
                                             const float* __restrict__ inv_deg,
                                             const int* __restrict__ elist,
                                             uint16_t* __restrict__ agg_h,
                                             uint16_t* __restrict__ agg_l) {
    int l32 = threadIdx.x & 31;
    int node = blockIdx.x * 8 + (threadIdx.x >> 5);
    if (node >= N_NODES) return;
    int rs = row_start[node];
    int d = degv[node];
    const uint16_t* base = (l32 < 16) ? hm_h : hm_l;
    int j = (l32 & 15) * 8;                 // element offset of this lane's chunk
    float a[8];
#pragma unroll
    for (int k = 0; k < 8; ++k) a[k] = 0.f;
    int i = 0;
    for (; i + 4 <= d; i += 4) {
        int s0 = elist[rs + i];
        int s1 = elist[rs + i + 1];
        int s2 = elist[rs + i + 2];
        int s3 = elist[rs + i + 3];
        short8 w0 = *(const short8*)&base[(size_t)s0 * 128 + j];
        short8 w1 = *(const short8*)&base[(size_t)s1 * 128 + j];
        short8 w2 = *(const short8*)&base[(size_t)s2 * 128 + j];
        short8 w3 = *(const short8*)&base[(size_t)s3 * 128 + j];
#pragma unroll
        for (int k = 0; k < 8; ++k)
            a[k] += (bf2fs(w0[k]) + bf2fs(w1[k])) + (bf2fs(w2[k]) + bf2fs(w3[k]));
    }
    for (; i < d; ++i) {
        int s = elist[rs + i];
        short8 w = *(const short8*)&base[(size_t)s * 128 + j];
#pragma unroll
        for (int k = 0; k < 8; ++k) a[k] += bf2fs(w[k]);
    }
    float sc = inv_deg[node];
    short8 outv;
#pragma unroll
    for (int k = 0; k < 8; ++k) {
        float v = (a[k] + __shfl_xor(a[k], 16)) * sc;
        uint16_t h = f2bf(v);
        outv[k] = (l32 < 16) ? (short)h : (short)f2bf(v - bf2f(h));
    }
    uint16_t* dstp = (l32 < 16) ? agg_h : agg_l;
    *(short8*)&dstp[(size_t)node * 128 + j] = outv;
}

// -------------- weight prep: transpose W[k][col] -> img[col][k], bf16 hi + lo
// 64 blocks per matrix (6 matrices, grid=384)
__global__ __launch_bounds__(256) void k_prepw(const float* Wl0, const float* Wr0,
                                               const float* Wl1, const float* Wr1,
                                               const float* Wl2, const float* Wr2,
                                               uint16_t* __restrict__ img) {
    int b = blockIdx.x >> 6;
    int sub = blockIdx.x & 63;
    const float* W; int ncol, npad; uint16_t* o;
    switch (b) {
        case 0: W = Wl0; ncol = 128; npad = 128; o = img;           break;
        case 1: W = Wr0; ncol = 128; npad = 128; o = img + 32768;   break;
        case 2: W = Wl1; ncol = 128; npad = 128; o = img + 65536;   break;
        case 3: W = Wr1; ncol = 128; npad = 128; o = img + 98304;   break;
        case 4: W = Wl2; ncol = 47;  npad = 48;  o = img + 131072;  break;
        default:W = Wr2; ncol = 47;  npad = 48;  o = img + 143360;  break;
    }
    int elems = npad * 128;
    int i = sub * 256 + threadIdx.x;
    if (i < elems) {
        int col = i % npad, k = i / npad;
        float v = (col < ncol) ? W[k * ncol + col] : 0.f;
        uint16_t h = f2bf(v);
        uint16_t l = f2bf(v - bf2f(h));
        int idx = col * 128 + k;
        o[idx] = h;
        o[idx + elems] = l;
    }
}

// ------- GEMM layers 0/1: out(hi/lo) = relu(A1@Wl + A2@Wr + b)
// Round-4 structure (measured best: 49 us): 128 rows/block, 4 waves,
// 32 rows/wave (2 row-tiles in flight), W streamed per col-tile from L2.
// Single delta vs round 4: A loads are pre-split bf16 hi/lo (no cvt VALU).
__global__ __launch_bounds__(256) void k_gemm(const uint16_t* __restrict__ A1h,
                                              const uint16_t* __restrict__ A1l,
                                              const uint16_t* __restrict__ A2h,
                                              const uint16_t* __restrict__ A2l,
                                              const uint16_t* __restrict__ wl,
                                              const uint16_t* __restrict__ wr,
                                              const float* __restrict__ bias,
                                              uint16_t* __restrict__ outh,
                                              uint16_t* __restrict__ outl) {
    int tid = threadIdx.x;
    int lane = tid & 63, wv = tid >> 6;
    int li = lane & 15, g4 = lane >> 4;
    int mrow = blockIdx.x * 128 + wv * 32 + li;
    int r0 = min(mrow, N_NODES - 1);
    int r1 = min(mrow + 16, N_NODES - 1);

    f32x4 acc[2][8];
#pragma unroll
    for (int m = 0; m < 2; ++m)
#pragma unroll
        for (int t = 0; t < 8; ++t) acc[m][t] = (f32x4){0.f, 0.f, 0.f, 0.f};

#pragma unroll
    for (int arr = 0; arr < 2; ++arr) {
        const uint16_t* Ah = arr ? A2h : A1h;
        const uint16_t* Al = arr ? A2l : A1l;
        const uint16_t* W  = arr ? wr : wl;
#pragma unroll
        for (int s = 0; s < 4; ++s) {
            int ko = s * 32 + g4 * 8;
            short8 a0h = *(const short8*)&Ah[(size_t)r0 * 128 + ko];
            short8 a0l = *(const short8*)&Al[(size_t)r0 * 128 + ko];
            short8 a1h = *(const short8*)&Ah[(size_t)r1 * 128 + ko];
            short8 a1l = *(const short8*)&Al[(size_t)r1 * 128 + ko];
#pragma unroll
            for (int t = 0; t < 8; ++t) {
                const uint16_t* p = &W[(t * 16 + li) * 128 + ko];
                short8 bh = *(const short8*)p;
                short8 bl = *(const short8*)(p + 16384);
                acc[0][t] = __builtin_amdgcn_mfma_f32_16x16x32_bf16(a0h, bh, acc[0][t], 0, 0, 0);
                acc[0][t] = __builtin_amdgcn_mfma_f32_16x16x32_bf16(a0l, bh, acc[0][t], 0, 0, 0);
                acc[0][t] = __builtin_amdgcn_mfma_f32_16x16x32_bf16(a0h, bl, acc[0][t], 0, 0, 0);
                acc[1][t] = __builtin_amdgcn_mfma_f32_16x16x32_bf16(a1h, bh, acc[1][t], 0, 0, 0);
                acc[1][t] = __builtin_amdgcn_mfma_f32_16x16x32_bf16(a1l, bh, acc[1][t], 0, 0, 0);
                acc[1][t] = __builtin_amdgcn_mfma_f32_16x16x32_bf16(a1h, bl, acc[1][t], 0, 0, 0);
            }
        }
    }
    // epilogue: bias + relu, split hi/lo.  D layout: col=lane&15, row=(lane>>4)*4+rr
    int rowbase = blockIdx.x * 128 + wv * 32 + g4 * 4;
#pragma unroll
    for (int t = 0; t < 8; ++t) {
        int col = t * 16 + li;
        float bv = bias[col];
#pragma unroll
        for (int m = 0; m < 2; ++m) {
#pragma unroll
            for (int rr = 0; rr < 4; ++rr) {
                int row = rowbase + m * 16 + rr;
                if (row < N_NODES) {
                    float v = fmaxf(acc[m][t][rr] + bv, 0.f);
                    uint16_t h = f2bf(v);
                    outh[(size_t)row * 128 + col] = h;
                    outl[(size_t)row * 128 + col] = f2bf(v - bf2f(h));
                }
            }
        }
    }
}

// -------- layer 2 GEMM fused with L2-normalize + log_softmax, out f32[N][47]
__global__ __launch_bounds__(256) void k_gemm2(const uint16_t* __restrict__ A1h,
                                               const uint16_t* __restrict__ A1l,
                                               const uint16_t* __restrict__ A2h,
                                               const uint16_t* __restrict__ A2l,
                                               const uint16_t* __restrict__ wl,
                                               const uint16_t* __restrict__ wr,
                                               const float* __restrict__ bias,
                                               float* __restrict__ out) {
    int tid = threadIdx.x;
    int lane = tid & 63, wv = tid >> 6;
    int li = lane & 15, g4 = lane >> 4;
    int mrow = blockIdx.x * 64 + wv * 16 + li;
    int r = min(mrow, N_NODES - 1);

    f32x4 acc[3];
#pragma unroll
    for (int t = 0; t < 3; ++t) acc[t] = (f32x4){0.f, 0.f, 0.f, 0.f};

#pragma unroll
    for (int arr = 0; arr < 2; ++arr) {
        const uint16_t* Ah = arr ? A2h : A1h;
        const uint16_t* Al = arr ? A2l : A1l;
        const uint16_t* W  = arr ? wr : wl;
#pragma unroll
        for (int s = 0; s < 4; ++s) {
            int ko = s * 32 + g4 * 8;
            short8 ah = *(const short8*)&Ah[(size_t)r * 128 + ko];
            short8 al = *(const short8*)&Al[(size_t)r * 128 + ko];
#pragma unroll
            for (int t = 0; t < 3; ++t) {
                const uint16_t* p = &W[(t * 16 + li) * 128 + ko];
                short8 bh = *(const short8*)p;
                short8 bl = *(const short8*)(p + 6144);
                acc[t] = __builtin_amdgcn_mfma_f32_16x16x32_bf16(ah, bh, acc[t], 0, 0, 0);
                acc[t] = __builtin_amdgcn_mfma_f32_16x16x32_bf16(al, bh, acc[t], 0, 0, 0);
                acc[t] = __builtin_amdgcn_mfma_f32_16x16x32_bf16(ah, bl, acc[t], 0, 0, 0);
            }
        }
    }

    float b0 = bias[li];
    float b1 = bias[16 + li];
    bool v2ok = (li < 15);
    float b2 = v2ok ? bias[32 + li] : 0.f;

    int rowbase = blockIdx.x * 64 + wv * 16 + g4 * 4;
#pragma unroll
    for (int rr = 0; rr < 4; ++rr) {
        int row = rowbase + rr;
        float v0 = acc[0][rr] + b0;
        float v1 = acc[1][rr] + b1;
        float v2 = v2ok ? (acc[2][rr] + b2) : 0.f;
        float ss = v0 * v0 + v1 * v1 + v2 * v2;
        ss += __shfl_xor(ss, 1);
        ss += __shfl_xor(ss, 2);
        ss += __shfl_xor(ss, 4);
        ss += __shfl_xor(ss, 8);
        float inv = 1.f / fmaxf(sqrtf(ss), 1e-12f);
        v0 *= inv; v1 *= inv; v2 *= inv;
        float mx = fmaxf(v0, v1);
        if (v2ok) mx = fmaxf(mx, v2);
        mx = fmaxf(mx, __shfl_xor(mx, 1));
        mx = fmaxf(mx, __shfl_xor(mx, 2));
        mx = fmaxf(mx, __shfl_xor(mx, 4));
        mx = fmaxf(mx, __shfl_xor(mx, 8));
        float se = expf(v0 - mx) + expf(v1 - mx) + (v2ok ? expf(v2 - mx) : 0.f);
        se += __shfl_xor(se, 1);
        se += __shfl_xor(se, 2);
        se += __shfl_xor(se, 4);
        se += __shfl_xor(se, 8);
        float lse = logf(se);
        if (row < N_NODES) {
            size_t ob = (size_t)row * NCLS;
            out[ob + li]      = v0 - mx - lse;
            out[ob + 16 + li] = v1 - mx - lse;
            if (v2ok) out[ob + 32 + li] = v2 - mx - lse;
        }
    }
}

// ---------------------------------------------------------------------------
extern "C" void kernel_launch(void* const* d_in, const int* in_sizes, int n_in,
                              void* d_out, int out_size, void* d_ws, size_t ws_size,
                              hipStream_t stream) {
    const float* x   = (const float*)d_in[0];
    const int*   ei  = (const int*)d_in[1];
    const float* Wl0 = (const float*)d_in[2];
    const float* bl0 = (const float*)d_in[3];
    const float* Wr0 = (const float*)d_in[4];
    const float* Wl1 = (const float*)d_in[5];
    const float* bl1 = (const float*)d_in[6];
    const float* Wr1 = (const float*)d_in[7];
    const float* Wl2 = (const float*)d_in[8];
    const float* bl2 = (const float*)d_in[9];
    const float* Wr2 = (const float*)d_in[10];
    float* out = (float*)d_out;

    char* ws = (char*)d_ws;
    size_t cur = 0;
    auto alloc = [&](size_t bytes) {
        char* p = ws + cur;
        cur += (bytes + 255) & ~(size_t)255;
        return p;
    };
    const size_t MATB = (size_t)N_NODES * 128 * 2;   // bf16 matrix bytes
    int*      deg       = (int*)alloc(N_NODES * 4);
    int*      row_start = (int*)alloc(N_NODES * 4);
    int*      fill      = (int*)alloc(N_NODES * 4);
    float*    inv_deg   = (float*)alloc(N_NODES * 4);
    int*      partial   = (int*)alloc(SCAN_BLOCKS * 4);
    int*      src       = (int*)alloc(N_EDGES * 4);
    int*      dst       = (int*)alloc(N_EDGES * 4);
    int*      elist     = (int*)alloc(N_EDGES * 4);
    uint16_t* wimg      = (uint16_t*)alloc(155648 * 2);
    uint16_t* xh        = (uint16_t*)alloc(MATB);
    uint16_t* xl        = (uint16_t*)alloc(MATB);
    uint16_t* Ah        = (uint16_t*)alloc(MATB);
    uint16_t* Al        = (uint16_t*)alloc(MATB);
    uint16_t* Bh        = (uint16_t*)alloc(MATB);
    uint16_t* Bl        = (uint16_t*)alloc(MATB);
    uint16_t* Ch        = (uint16_t*)alloc(MATB);
    uint16_t* Cl        = (uint16_t*)alloc(MATB);

    hipMemsetAsync(deg, 0, N_NODES * 4, stream);
    k_prepw<<<384, 256, 0, stream>>>(Wl0, Wr0, Wl1, Wr1, Wl2, Wr2, wimg);
    k_split<<<(N_NODES * 128 / 4) / 256, 256, 0, stream>>>((const float4*)x,
                                                           (ushort4*)xh, (ushort4*)xl);

    int egrid = (N_EDGES + 255) / 256;
    k_cvt_idx<<<egrid, 256, 0, stream>>>(ei, src, dst, deg);
    k_scan1<<<SCAN_BLOCKS, SCAN_TPB, 0, stream>>>(deg, partial);
    k_scan2<<<1, 128, 0, stream>>>(partial);
    k_scan3<<<SCAN_BLOCKS, SCAN_TPB, 0, stream>>>(deg, partial, row_start, fill, inv_deg);
    k_fill<<<egrid, 256, 0, stream>>>(src, dst, fill, elist);

    int agrid = (N_NODES + 7) / 8;           // 6250
    int ggrid = (N_NODES + 127) / 128;       // 391
    int g2grid = (N_NODES + 63) / 64;        // 782

    // layer 0
    k_agg<<<agrid, 256, 0, stream>>>(xh, xl, row_start, deg, inv_deg, elist, Ah, Al);
    k_gemm<<<ggrid, 256, 0, stream>>>(Ah, Al, xh, xl, wimg, wimg + 32768, bl0, Bh, Bl);
    // layer 1
    k_agg<<<agrid, 256, 0, stream>>>(Bh, Bl, row_start, deg, inv_deg, elist, Ah, Al);
    k_gemm<<<ggrid, 256, 0, stream>>>(Ah, Al, Bh, Bl, wimg + 65536, wimg + 98304, bl1, Ch, Cl);
    // layer 2 (fused normalize + log_softmax)
    k_agg<<<agrid, 256, 0, stream>>>(Ch, Cl, row_start, deg, inv_deg, elist, Ah, Al);
    k_gemm2<<<g2grid, 256, 0, stream>>>(Ah, Al, Ch, Cl, wimg + 131072, wimg + 143360, bl2, out);
}

// Round 9
// 415.927 us; speedup vs baseline: 1.1501x; 1.0377x over previous
//
#include <hip/hip_runtime.h>
#include <stdint.h>

#define N_NODES 50000
#define N_EDGES 600000
#define NCLS    47
#define SCAN_TPB 512
#define SCAN_BLOCKS ((N_NODES + SCAN_TPB - 1) / SCAN_TPB)   // 98

typedef __attribute__((ext_vector_type(8))) short short8;
typedef __attribute__((ext_vector_type(4))) float f32x4;

static __device__ __forceinline__ float bf2f(uint16_t h) {
    union { uint32_t u; float f; } c; c.u = ((uint32_t)h) << 16; return c.f;
}
static __device__ __forceinline__ float bf2fs(short h) { return bf2f((uint16_t)h); }
static __device__ __forceinline__ uint16_t f2bf(float f) {
    union { float f; uint32_t u; } c; c.f = f;
    uint32_t u = c.u;
    return (uint16_t)((u + 0x7fffu + ((u >> 16) & 1u)) >> 16); // RNE
}

// ---------------- split f32 matrix -> bf16 hi + bf16 lo arrays (x only)
__global__ __launch_bounds__(256) void k_split(const float4* __restrict__ x,
                                               ushort4* __restrict__ xh,
                                               ushort4* __restrict__ xl) {
    int i = blockIdx.x * 256 + threadIdx.x;   // 1.6M float4s
    float4 v = x[i];
    ushort4 h, l;
    h.x = f2bf(v.x); l.x = f2bf(v.x - bf2f(h.x));
    h.y = f2bf(v.y); l.y = f2bf(v.y - bf2f(h.y));
    h.z = f2bf(v.z); l.z = f2bf(v.z - bf2f(h.z));
    h.w = f2bf(v.w); l.w = f2bf(v.w - bf2f(h.w));
    xh[i] = h;
    xl[i] = l;
}

// ---------- edge_index canonicalize (int64-or-int32 -> int32) + degree count
__global__ __launch_bounds__(256) void k_cvt_idx(const int* __restrict__ ei,
                                                 int* __restrict__ src,
                                                 int* __restrict__ dst,
                                                 int* __restrict__ deg) {
    __shared__ int is64;
    {
        int lane = threadIdx.x;
        if (lane < 64) {
            int f = ei[2 * lane + 1] | ei[2 * lane + 129]; // 128 hi-words if int64
            unsigned long long m = __ballot(f != 0);
            if (lane == 0) is64 = (m == 0ULL) ? 1 : 0;
        }
        __syncthreads();
    }
    int e = blockIdx.x * 256 + threadIdx.x;
    if (e < N_EDGES) {
        int s, d;
        if (is64) { s = ei[2 * e]; d = ei[2 * (N_EDGES + e)]; }
        else      { s = ei[e];     d = ei[N_EDGES + e]; }
        s = min(max(s, 0), N_NODES - 1);
        d = min(max(d, 0), N_NODES - 1);
        src[e] = s;
        dst[e] = d;
        atomicAdd(&deg[d], 1);
    }
}

// ------------------------------------------- scan stage 1: per-block partials
__global__ __launch_bounds__(SCAN_TPB) void k_scan1(const int* __restrict__ deg,
                                                    int* __restrict__ partial) {
    int t = blockIdx.x * SCAN_TPB + threadIdx.x;
    int v = (t < N_NODES) ? deg[t] : 0;
#pragma unroll
    for (int o = 1; o < 64; o <<= 1) v += __shfl_xor(v, o);
    __shared__ int ws[SCAN_TPB / 64];
    int lane = threadIdx.x & 63, w = threadIdx.x >> 6;
    if (lane == 0) ws[w] = v;
    __syncthreads();
    if (threadIdx.x == 0) {
        int s = 0;
#pragma unroll
        for (int i = 0; i < SCAN_TPB / 64; ++i) s += ws[i];
        partial[blockIdx.x] = s;
    }
}

// ---------------------------- scan stage 2: exclusive scan of 98 partials
__global__ __launch_bounds__(128) void k_scan2(int* __restrict__ partial) {
    __shared__ int sh[128];
    int t = threadIdx.x;
    int v = (t < SCAN_BLOCKS) ? partial[t] : 0;
    sh[t] = v;
    __syncthreads();
    for (int o = 1; o < 128; o <<= 1) {
        int u = (t >= o) ? sh[t - o] : 0;
        __syncthreads();
        sh[t] += u;
        __syncthreads();
    }
    if (t < SCAN_BLOCKS) partial[t] = sh[t] - v; // exclusive
}

// --------------- scan stage 3: block-local exclusive scan + offset, emit CSR
__global__ __launch_bounds__(SCAN_TPB) void k_scan3(const int* __restrict__ deg,
                                                    const int* __restrict__ partial,
                                                    int* __restrict__ row_start,
                                                    int* __restrict__ fill,
                                                    float* __restrict__ inv_deg) {
    int tb = threadIdx.x;
    int t = blockIdx.x * SCAN_TPB + tb;
    int v = (t < N_NODES) ? deg[t] : 0;
    int lane = tb & 63, w = tb >> 6;
    int inc = v;
#pragma unroll
    for (int o = 1; o < 64; o <<= 1) {
        int u = __shfl_up(inc, o);
        if (lane >= o) inc += u;
    }
    __shared__ int wsum[SCAN_TPB / 64];
    if (lane == 63) wsum[w] = inc;
    __syncthreads();
    int woff = 0;
    for (int i = 0; i < w; ++i) woff += wsum[i];
    int excl = partial[blockIdx.x] + woff + (inc - v);
    if (t < N_NODES) {
        row_start[t] = excl;
        fill[t] = excl;
        inv_deg[t] = 1.0f / (float)(v > 0 ? v : 1);
    }
}

// ---------------------------------------------------------------- bucket fill
__global__ __launch_bounds__(256) void k_fill(const int* __restrict__ src,
                                              const int* __restrict__ dst,
                                              int* __restrict__ fill,
                                              int* __restrict__ elist) {
    int e = blockIdx.x * 256 + threadIdx.x;
    if (e < N_EDGES) {
        int pos = atomicAdd(&fill[dst[e]], 1);
        elist[pos] = src[e];
    }
}

// -------- mean aggregation, hi/lo bf16 in & out (half-wave/node; lanes 0-15
// stream the hi array, lanes 16-31 the lo array; combine via shfl_xor(16))
__global__ __launch_bounds__(256) void k_agg(const uint16_t* __restrict__ hm_h,
                                             const uint16_t* __restrict__ hm_l,
                                             const int* __restrict__ row_start,
                                             const int* __restrict__ degv,
                                             const float* __restrict__ inv_deg,
                                             const int* __restrict__ elist,
                                             uint16_t* __restrict__ agg_h,
                                             uint16_t* __restrict__ agg_l) {
    int l32 = threadIdx.x & 31;
    int node = blockIdx.x * 8 + (threadIdx.x >> 5);
    if (node >= N_NODES) return;
    int rs = row_start[node];
    int d = degv[node];
    const uint16_t* base = (l32 < 16) ? hm_h : hm_l;
    int j = (l32 & 15) * 8;                 // element offset of this lane's chunk
    float a[8];
#pragma unroll
    for (int k = 0; k < 8; ++k) a[k] = 0.f;
    int i = 0;
    for (; i + 4 <= d; i += 4) {
        int s0 = elist[rs + i];
        int s1 = elist[rs + i + 1];
        int s2 = elist[rs + i + 2];
        int s3 = elist[rs + i + 3];
        short8 w0 = *(const short8*)&base[(size_t)s0 * 128 + j];
        short8 w1 = *(const short8*)&base[(size_t)s1 * 128 + j];
        short8 w2 = *(const short8*)&base[(size_t)s2 * 128 + j];
        short8 w3 = *(const short8*)&base[(size_t)s3 * 128 + j];
#pragma unroll
        for (int k = 0; k < 8; ++k)
            a[k] += (bf2fs(w0[k]) + bf2fs(w1[k])) + (bf2fs(w2[k]) + bf2fs(w3[k]));
    }
    for (; i < d; ++i) {
        int s = elist[rs + i];
        short8 w = *(const short8*)&base[(size_t)s * 128 + j];
#pragma unroll
        for (int k = 0; k < 8; ++k) a[k] += bf2fs(w[k]);
    }
    float sc = inv_deg[node];
    short8 outv;
#pragma unroll
    for (int k = 0; k < 8; ++k) {
        float v = (a[k] + __shfl_xor(a[k], 16)) * sc;
        uint16_t h = f2bf(v);
        outv[k] = (l32 < 16) ? (short)h : (short)f2bf(v - bf2f(h));
    }
    uint16_t* dstp = (l32 < 16) ? agg_h : agg_l;
    *(short8*)&dstp[(size_t)node * 128 + j] = outv;
}

// -------------- weight prep: transpose W[k][col] -> img[col][k], bf16 hi + lo
// Matrices 0-3 (128-col, used by LDS k_gemm) get a bank-conflict swizzle
// baked into the image: chunk (k>>3) XOR'd with (col&15). Staging to LDS is
// then a linear identity copy; ds_read applies the same XOR.
__global__ __launch_bounds__(256) void k_prepw(const float* Wl0, const float* Wr0,
                                               const float* Wl1, const float* Wr1,
                                               const float* Wl2, const float* Wr2,
                                               uint16_t* __restrict__ img) {
    int b = blockIdx.x >> 6;
    int sub = blockIdx.x & 63;
    const float* W; int ncol, npad; uint16_t* o;
    switch (b) {
        case 0: W = Wl0; ncol = 128; npad = 128; o = img;           break;
        case 1: W = Wr0; ncol = 128; npad = 128; o = img + 32768;   break;
        case 2: W = Wl1; ncol = 128; npad = 128; o = img + 65536;   break;
        case 3: W = Wr1; ncol = 128; npad = 128; o = img + 98304;   break;
        case 4: W = Wl2; ncol = 47;  npad = 48;  o = img + 131072;  break;
        default:W = Wr2; ncol = 47;  npad = 48;  o = img + 143360;  break;
    }
    int elems = npad * 128;
    int i = sub * 256 + threadIdx.x;
    if (i < elems) {
        int col = i % npad, k = i / npad;
        float v = (col < ncol) ? W[k * ncol + col] : 0.f;
        uint16_t h = f2bf(v);
        uint16_t l = f2bf(v - bf2f(h));
        int idx;
        if (b < 4) idx = col * 128 + (((k >> 3) ^ (col & 15)) << 3) + (k & 7);
        else       idx = col * 128 + k;
        o[idx] = h;
        o[idx + elems] = l;
    }
}

// ------- GEMM layers 0/1: out(hi/lo) = relu(A1@Wl + A2@Wr + b)
// Round-4 shape (128 rows/block, 4 waves, 32 rows/wave) + LDS-resident W:
// per arr-phase, stage one matrix (hi+lo, 64 KB) into LDS with a linear
// uint4 copy (image is pre-swizzled), inner loop reads ds_read_b128.
__global__ __launch_bounds__(256) void k_gemm(const uint16_t* __restrict__ A1h,
                                              const uint16_t* __restrict__ A1l,
                                              const uint16_t* __restrict__ A2h,
                                              const uint16_t* __restrict__ A2l,
                                              const uint16_t* __restrict__ wl,
                                              const uint16_t* __restrict__ wr,
                                              const float* __restrict__ bias,
                                              uint16_t* __restrict__ outh,
                                              uint16_t* __restrict__ outl) {
    __shared__ __align__(16) uint16_t ldsW[32768];   // 64 KB: one matrix hi+lo
    int tid = threadIdx.x;
    int lane = tid & 63, wv = tid >> 6;
    int li = lane & 15, g4 = lane >> 4;
    int mrow = blockIdx.x * 128 + wv * 32 + li;
    int r0 = min(mrow, N_NODES - 1);
    int r1 = min(mrow + 16, N_NODES - 1);

    f32x4 acc[2][8];
#pragma unroll
    for (int m = 0; m < 2; ++m)
#pragma unroll
        for (int t = 0; t < 8; ++t) acc[m][t] = (f32x4){0.f, 0.f, 0.f, 0.f};

#pragma unroll
    for (int arr = 0; arr < 2; ++arr) {
        // stage this arr's weight image (linear copy; swizzle pre-applied)
        {
            const uint4* g = (const uint4*)(arr ? wr : wl);
            uint4* l = (uint4*)ldsW;
#pragma unroll
            for (int j2 = 0; j2 < 32; ++j2)
                l[j2 * 256 + tid] = g[j2 * 256 + tid];
        }
        __syncthreads();

        const uint16_t* Ah = arr ? A2h : A1h;
        const uint16_t* Al = arr ? A2l : A1l;
#pragma unroll
        for (int s = 0; s < 4; ++s) {
            int ko = s * 32 + g4 * 8;
            short8 a0h = *(const short8*)&Ah[(size_t)r0 * 128 + ko];
            short8 a0l = *(const short8*)&Al[(size_t)r0 * 128 + ko];
            short8 a1h = *(const short8*)&Ah[(size_t)r1 * 128 + ko];
            short8 a1l = *(const short8*)&Al[(size_t)r1 * 128 + ko];
#pragma unroll
            for (int t = 0; t < 8; ++t) {
                int off = (t * 16 + li) * 128 + (((s * 4 + g4) ^ li) << 3);
                short8 bh = *(const short8*)&ldsW[off];
                short8 bl = *(const short8*)&ldsW[off + 16384];
                acc[0][t] = __builtin_amdgcn_mfma_f32_16x16x32_bf16(a0h, bh, acc[0][t], 0, 0, 0);
                acc[0][t] = __builtin_amdgcn_mfma_f32_16x16x32_bf16(a0l, bh, acc[0][t], 0, 0, 0);
                acc[0][t] = __builtin_amdgcn_mfma_f32_16x16x32_bf16(a0h, bl, acc[0][t], 0, 0, 0);
                acc[1][t] = __builtin_amdgcn_mfma_f32_16x16x32_bf16(a1h, bh, acc[1][t], 0, 0, 0);
                acc[1][t] = __builtin_amdgcn_mfma_f32_16x16x32_bf16(a1l, bh, acc[1][t], 0, 0, 0);
                acc[1][t] = __builtin_amdgcn_mfma_f32_16x16x32_bf16(a1h, bl, acc[1][t], 0, 0, 0);
            }
        }
        if (arr == 0) __syncthreads();   // drain reads before restaging
    }
    // epilogue: bias + relu, split hi/lo.  D layout: col=lane&15, row=(lane>>4)*4+rr
    int rowbase = blockIdx.x * 128 + wv * 32 + g4 * 4;
#pragma unroll
    for (int t = 0; t < 8; ++t) {
        int col = t * 16 + li;
        float bv = bias[col];
#pragma unroll
        for (int m = 0; m < 2; ++m) {
#pragma unroll
            for (int rr = 0; rr < 4; ++rr) {
                int row = rowbase + m * 16 + rr;
                if (row < N_NODES) {
                    float v = fmaxf(acc[m][t][rr] + bv, 0.f);
                    uint16_t h = f2bf(v);
                    outh[(size_t)row * 128 + col] = h;
                    outl[(size_t)row * 128 + col] = f2bf(v - bf2f(h));
                }
            }
        }
    }
}

// -------- layer 2 GEMM fused with L2-normalize + log_softmax, out f32[N][47]
__global__ __launch_bounds__(256) void k_gemm2(const uint16_t* __restrict__ A1h,
                                               const uint16_t* __restrict__ A1l,
                                               const uint16_t* __restrict__ A2h,
                                               const uint16_t* __restrict__ A2l,
                                               const uint16_t* __restrict__ wl,
                                               const uint16_t* __restrict__ wr,
                                               const float* __restrict__ bias,
                                               float* __restrict__ out) {
    int tid = threadIdx.x;
    int lane = tid & 63, wv = tid >> 6;
    int li = lane & 15, g4 = lane >> 4;
    int mrow = blockIdx.x * 64 + wv * 16 + li;
    int r = min(mrow, N_NODES - 1);

    f32x4 acc[3];
#pragma unroll
    for (int t = 0; t < 3; ++t) acc[t] = (f32x4){0.f, 0.f, 0.f, 0.f};

#pragma unroll
    for (int arr = 0; arr < 2; ++arr) {
        const uint16_t* Ah = arr ? A2h : A1h;
        const uint16_t* Al = arr ? A2l : A1l;
        const uint16_t* W  = arr ? wr : wl;
#pragma unroll
        for (int s = 0; s < 4; ++s) {
            int ko = s * 32 + g4 * 8;
            short8 ah = *(const short8*)&Ah[(size_t)r * 128 + ko];
            short8 al = *(const short8*)&Al[(size_t)r * 128 + ko];
#pragma unroll
            for (int t = 0; t < 3; ++t) {
                const uint16_t* p = &W[(t * 16 + li) * 128 + ko];
                short8 bh = *(const short8*)p;
                short8 bl = *(const short8*)(p + 6144);
                acc[t] = __builtin_amdgcn_mfma_f32_16x16x32_bf16(ah, bh, acc[t], 0, 0, 0);
                acc[t] = __builtin_amdgcn_mfma_f32_16x16x32_bf16(al, bh, acc[t], 0, 0, 0);
                acc[t] = __builtin_amdgcn_mfma_f32_16x16x32_bf16(ah, bl, acc[t], 0, 0, 0);
            }
        }
    }

    float b0 = bias[li];
    float b1 = bias[16 + li];
    bool v2ok = (li < 15);
    float b2 = v2ok ? bias[32 + li] : 0.f;

    int rowbase = blockIdx.x * 64 + wv * 16 + g4 * 4;
#pragma unroll
    for (int rr = 0; rr < 4; ++rr) {
        int row = rowbase + rr;
        float v0 = acc[0][rr] + b0;
        float v1 = acc[1][rr] + b1;
        float v2 = v2ok ? (acc[2][rr] + b2) : 0.f;
        float ss = v0 * v0 + v1 * v1 + v2 * v2;
        ss += __shfl_xor(ss, 1);
        ss += __shfl_xor(ss, 2);
        ss += __shfl_xor(ss, 4);
        ss += __shfl_xor(ss, 8);
        float inv = 1.f / fmaxf(sqrtf(ss), 1e-12f);
        v0 *= inv; v1 *= inv; v2 *= inv;
        float mx = fmaxf(v0, v1);
        if (v2ok) mx = fmaxf(mx, v2);
        mx = fmaxf(mx, __shfl_xor(mx, 1));
        mx = fmaxf(mx, __shfl_xor(mx, 2));
        mx = fmaxf(mx, __shfl_xor(mx, 4));
        mx = fmaxf(mx, __shfl_xor(mx, 8));
        float se = expf(v0 - mx) + expf(v1 - mx) + (v2ok ? expf(v2 - mx) : 0.f);
        se += __shfl_xor(se, 1);
        se += __shfl_xor(se, 2);
        se += __shfl_xor(se, 4);
        se += __shfl_xor(se, 8);
        float lse = logf(se);
        if (row < N_NODES) {
            size_t ob = (size_t)row * NCLS;
            out[ob + li]      = v0 - mx - lse;
            out[ob + 16 + li] = v1 - mx - lse;
            if (v2ok) out[ob + 32 + li] = v2 - mx - lse;
        }
    }
}

// ---------------------------------------------------------------------------
extern "C" void kernel_launch(void* const* d_in, const int* in_sizes, int n_in,
                              void* d_out, int out_size, void* d_ws, size_t ws_size,
                              hipStream_t stream) {
    const float* x   = (const float*)d_in[0];
    const int*   ei  = (const int*)d_in[1];
    const float* Wl0 = (const float*)d_in[2];
    const float* bl0 = (const float*)d_in[3];
    const float* Wr0 = (const float*)d_in[4];
    const float* Wl1 = (const float*)d_in[5];
    const float* bl1 = (const float*)d_in[6];
    const float* Wr1 = (const float*)d_in[7];
    const float* Wl2 = (const float*)d_in[8];
    const float* bl2 = (const float*)d_in[9];
    const float* Wr2 = (const float*)d_in[10];
    float* out = (float*)d_out;

    char* ws = (char*)d_ws;
    size_t cur = 0;
    auto alloc = [&](size_t bytes) {
        char* p = ws + cur;
        cur += (bytes + 255) & ~(size_t)255;
        return p;
    };
    const size_t MATB = (size_t)N_NODES * 128 * 2;   // bf16 matrix bytes
    int*      deg       = (int*)alloc(N_NODES * 4);
    int*      row_start = (int*)alloc(N_NODES * 4);
    int*      fill      = (int*)alloc(N_NODES * 4);
    float*    inv_deg   = (float*)alloc(N_NODES * 4);
    int*      partial   = (int*)alloc(SCAN_BLOCKS * 4);
    int*      src       = (int*)alloc(N_EDGES * 4);
    int*      dst       = (int*)alloc(N_EDGES * 4);
    int*      elist     = (int*)alloc(N_EDGES * 4);
    uint16_t* wimg      = (uint16_t*)alloc(155648 * 2);
    uint16_t* xh        = (uint16_t*)alloc(MATB);
    uint16_t* xl        = (uint16_t*)alloc(MATB);
    uint16_t* Ah        = (uint16_t*)alloc(MATB);
    uint16_t* Al        = (uint16_t*)alloc(MATB);
    uint16_t* Bh        = (uint16_t*)alloc(MATB);
    uint16_t* Bl        = (uint16_t*)alloc(MATB);
    uint16_t* Ch        = (uint16_t*)alloc(MATB);
    uint16_t* Cl        = (uint16_t*)alloc(MATB);

    hipMemsetAsync(deg, 0, N_NODES * 4, stream);
    k_prepw<<<384, 256, 0, stream>>>(Wl0, Wr0, Wl1, Wr1, Wl2, Wr2, wimg);
    k_split<<<(N_NODES * 128 / 4) / 256, 256, 0, stream>>>((const float4*)x,
                                                           (ushort4*)xh, (ushort4*)xl);

    int egrid = (N_EDGES + 255) / 256;
    k_cvt_idx<<<egrid, 256, 0, stream>>>(ei, src, dst, deg);
    k_scan1<<<SCAN_BLOCKS, SCAN_TPB, 0, stream>>>(deg, partial);
    k_scan2<<<1, 128, 0, stream>>>(partial);
    k_scan3<<<SCAN_BLOCKS, SCAN_TPB, 0, stream>>>(deg, partial, row_start, fill, inv_deg);
    k_fill<<<egrid, 256, 0, stream>>>(src, dst, fill, elist);

    int agrid = (N_NODES + 7) / 8;           // 6250
    int ggrid = (N_NODES + 127) / 128;       // 391
    int g2grid = (N_NODES + 63) / 64;        // 782

    // layer 0
    k_agg<<<agrid, 256, 0, stream>>>(xh, xl, row_start, deg, inv_deg, elist, Ah, Al);
    k_gemm<<<ggrid, 256, 0, stream>>>(Ah, Al, xh, xl, wimg, wimg + 32768, bl0, Bh, Bl);
    // layer 1
    k_agg<<<agrid, 256, 0, stream>>>(Bh, Bl, row_start, deg, inv_deg, elist, Ah, Al);
    k_gemm<<<ggrid, 256, 0, stream>>>(Ah, Al, Bh, Bl, wimg + 65536, wimg + 98304, bl1, Ch, Cl);
    // layer 2 (fused normalize + log_softmax)
    k_agg<<<agrid, 256, 0, stream>>>(Ch, Cl, row_start, deg, inv_deg, elist, Ah, Al);
    k_gemm2<<<g2grid, 256, 0, stream>>>(Ah, Al, Ch, Cl, wimg + 131072, wimg + 143360, bl2, out);
}

// Round 10
// 366.198 us; speedup vs baseline: 1.3063x; 1.1358x over previous
//
#include <hip/hip_runtime.h>
#include <stdint.h>

#define N_NODES 50000
#define N_EDGES 600000
#define NCLS    47
#define SCAN_TPB 512
#define SCAN_BLOCKS ((N_NODES + SCAN_TPB - 1) / SCAN_TPB)   // 98

typedef __attribute__((ext_vector_type(8))) short short8;
typedef __attribute__((ext_vector_type(4))) float f32x4;

static __device__ __forceinline__ float bf2f(uint16_t h) {
    union { uint32_t u; float f; } c; c.u = ((uint32_t)h) << 16; return c.f;
}
static __device__ __forceinline__ float bf2fs(short h) { return bf2f((uint16_t)h); }
static __device__ __forceinline__ uint16_t f2bf(float f) {
    union { float f; uint32_t u; } c; c.f = f;
    uint32_t u = c.u;
    return (uint16_t)((u + 0x7fffu + ((u >> 16) & 1u)) >> 16); // RNE
}

// ---------------- split f32 matrix -> bf16 hi + bf16 lo arrays (x only)
__global__ __launch_bounds__(256) void k_split(const float4* __restrict__ x,
                                               ushort4* __restrict__ xh,
                                               ushort4* __restrict__ xl) {
    int i = blockIdx.x * 256 + threadIdx.x;   // 1.6M float4s
    float4 v = x[i];
    ushort4 h, l;
    h.x = f2bf(v.x); l.x = f2bf(v.x - bf2f(h.x));
    h.y = f2bf(v.y); l.y = f2bf(v.y - bf2f(h.y));
    h.z = f2bf(v.z); l.z = f2bf(v.z - bf2f(h.z));
    h.w = f2bf(v.w); l.w = f2bf(v.w - bf2f(h.w));
    xh[i] = h;
    xl[i] = l;
}

// ---------- edge_index canonicalize (int64-or-int32 -> int32) + degree count
__global__ __launch_bounds__(256) void k_cvt_idx(const int* __restrict__ ei,
                                                 int* __restrict__ src,
                                                 int* __restrict__ dst,
                                                 int* __restrict__ deg) {
    __shared__ int is64;
    {
        int lane = threadIdx.x;
        if (lane < 64) {
            int f = ei[2 * lane + 1] | ei[2 * lane + 129]; // 128 hi-words if int64
            unsigned long long m = __ballot(f != 0);
            if (lane == 0) is64 = (m == 0ULL) ? 1 : 0;
        }
        __syncthreads();
    }
    int e = blockIdx.x * 256 + threadIdx.x;
    if (e < N_EDGES) {
        int s, d;
        if (is64) { s = ei[2 * e]; d = ei[2 * (N_EDGES + e)]; }
        else      { s = ei[e];     d = ei[N_EDGES + e]; }
        s = min(max(s, 0), N_NODES - 1);
        d = min(max(d, 0), N_NODES - 1);
        src[e] = s;
        dst[e] = d;
        atomicAdd(&deg[d], 1);
    }
}

// ------------------------------------------- scan stage 1: per-block partials
__global__ __launch_bounds__(SCAN_TPB) void k_scan1(const int* __restrict__ deg,
                                                    int* __restrict__ partial) {
    int t = blockIdx.x * SCAN_TPB + threadIdx.x;
    int v = (t < N_NODES) ? deg[t] : 0;
#pragma unroll
    for (int o = 1; o < 64; o <<= 1) v += __shfl_xor(v, o);
    __shared__ int ws[SCAN_TPB / 64];
    int lane = threadIdx.x & 63, w = threadIdx.x >> 6;
    if (lane == 0) ws[w] = v;
    __syncthreads();
    if (threadIdx.x == 0) {
        int s = 0;
#pragma unroll
        for (int i = 0; i < SCAN_TPB / 64; ++i) s += ws[i];
        partial[blockIdx.x] = s;
    }
}

// ---------------------------- scan stage 2: exclusive scan of 98 partials
__global__ __launch_bounds__(128) void k_scan2(int* __restrict__ partial) {
    __shared__ int sh[128];
    int t = threadIdx.x;
    int v = (t < SCAN_BLOCKS) ? partial[t] : 0;
    sh[t] = v;
    __syncthreads();
    for (int o = 1; o < 128; o <<= 1) {
        int u = (t >= o) ? sh[t - o] : 0;
        __syncthreads();
        sh[t] += u;
        __syncthreads();
    }
    if (t < SCAN_BLOCKS) partial[t] = sh[t] - v; // exclusive
}

// --------------- scan stage 3: block-local exclusive scan + offset, emit CSR
__global__ __launch_bounds__(SCAN_TPB) void k_scan3(const int* __restrict__ deg,
                                                    const int* __restrict__ partial,
                                                    int* __restrict__ row_start,
                                                    int* __restrict__ fill,
                                                    float* __restrict__ inv_deg) {
    int tb = threadIdx.x;
    int t = blockIdx.x * SCAN_TPB + tb;
    int v = (t < N_NODES) ? deg[t] : 0;
    int lane = tb & 63, w = tb >> 6;
    int inc = v;
#pragma unroll
    for (int o = 1; o < 64; o <<= 1) {
        int u = __shfl_up(inc, o);
        if (lane >= o) inc += u;
    }
    __shared__ int wsum[SCAN_TPB / 64];
    if (lane == 63) wsum[w] = inc;
    __syncthreads();
    int woff = 0;
    for (int i = 0; i < w; ++i) woff += wsum[i];
    int excl = partial[blockIdx.x] + woff + (inc - v);
    if (t < N_NODES) {
        row_start[t] = excl;
        fill[t] = excl;
        inv_deg[t] = 1.0f / (float)(v > 0 ? v : 1);
    }
}

// ---------------------------------------------------------------- bucket fill
__global__ __launch_bounds__(256) void k_fill(const int* __restrict__ src,
                                              const int* __restrict__ dst,
                                              int* __restrict__ fill,
                                              int* __restrict__ elist) {
    int e = blockIdx.x * 256 + threadIdx.x;
    if (e < N_EDGES) {
        int pos = atomicAdd(&fill[dst[e]], 1);
        elist[pos] = src[e];
    }
}

// -------- mean aggregation, HI-ONLY input (halves gather traffic), hi/lo out.
// 1 wave/node: 4 edge-groups x 16 lanes, 2-deep unroll, shfl cross-group sum.
__global__ __launch_bounds__(256) void k_agg(const uint16_t* __restrict__ hm_h,
                                             const int* __restrict__ row_start,
                                             const int* __restrict__ degv,
                                             const float* __restrict__ inv_deg,
                                             const int* __restrict__ elist,
                                             uint16_t* __restrict__ agg_h,
                                             uint16_t* __restrict__ agg_l) {
    int lane = threadIdx.x & 63;
    int node = blockIdx.x * 4 + (threadIdx.x >> 6);
    if (node >= N_NODES) return;
    int g = lane >> 4;                      // edge-group 0..3
    int li = lane & 15;
    int j = li * 8;                         // this lane's 8-elem chunk
    int rs = row_start[node];
    int d = degv[node];
    float a[8];
#pragma unroll
    for (int k = 0; k < 8; ++k) a[k] = 0.f;
    int i = g;
    for (; i + 4 < d; i += 8) {             // 2 gathers in flight per lane
        int s0 = elist[rs + i];
        int s1 = elist[rs + i + 4];
        short8 w0 = *(const short8*)&hm_h[(size_t)s0 * 128 + j];
        short8 w1 = *(const short8*)&hm_h[(size_t)s1 * 128 + j];
#pragma unroll
        for (int k = 0; k < 8; ++k) a[k] += bf2fs(w0[k]) + bf2fs(w1[k]);
    }
    if (i < d) {
        int s = elist[rs + i];
        short8 w = *(const short8*)&hm_h[(size_t)s * 128 + j];
#pragma unroll
        for (int k = 0; k < 8; ++k) a[k] += bf2fs(w[k]);
    }
    float sc = inv_deg[node];
    short8 oh, ol;
#pragma unroll
    for (int k = 0; k < 8; ++k) {
        float v = a[k];
        v += __shfl_xor(v, 16);
        v += __shfl_xor(v, 32);
        v *= sc;
        uint16_t h = f2bf(v);
        oh[k] = (short)h;
        ol[k] = (short)f2bf(v - bf2f(h));
    }
    if (g == 0)      *(short8*)&agg_h[(size_t)node * 128 + j] = oh;
    else if (g == 1) *(short8*)&agg_l[(size_t)node * 128 + j] = ol;
}

// -------------- weight prep: transpose W[k][col] -> img[col][k], bf16 hi + lo
// Matrices 0-3 (128-col, used by LDS k_gemm) get a bank-conflict swizzle
// baked into the image: chunk (k>>3) XOR'd with (col&15). Staging to LDS is
// then a linear identity copy; ds_read applies the same XOR.
__global__ __launch_bounds__(256) void k_prepw(const float* Wl0, const float* Wr0,
                                               const float* Wl1, const float* Wr1,
                                               const float* Wl2, const float* Wr2,
                                               uint16_t* __restrict__ img) {
    int b = blockIdx.x >> 6;
    int sub = blockIdx.x & 63;
    const float* W; int ncol, npad; uint16_t* o;
    switch (b) {
        case 0: W = Wl0; ncol = 128; npad = 128; o = img;           break;
        case 1: W = Wr0; ncol = 128; npad = 128; o = img + 32768;   break;
        case 2: W = Wl1; ncol = 128; npad = 128; o = img + 65536;   break;
        case 3: W = Wr1; ncol = 128; npad = 128; o = img + 98304;   break;
        case 4: W = Wl2; ncol = 47;  npad = 48;  o = img + 131072;  break;
        default:W = Wr2; ncol = 47;  npad = 48;  o = img + 143360;  break;
    }
    int elems = npad * 128;
    int i = sub * 256 + threadIdx.x;
    if (i < elems) {
        int col = i % npad, k = i / npad;
        float v = (col < ncol) ? W[k * ncol + col] : 0.f;
        uint16_t h = f2bf(v);
        uint16_t l = f2bf(v - bf2f(h));
        int idx;
        if (b < 4) idx = col * 128 + (((k >> 3) ^ (col & 15)) << 3) + (k & 7);
        else       idx = col * 128 + k;
        o[idx] = h;
        o[idx + elems] = l;
    }
}

// ------- GEMM layers 0/1: out(hi/lo) = relu(A1@Wl + A2@Wr + b)
// Round-4 shape (128 rows/block, 4 waves, 32 rows/wave) + LDS-resident W:
// per arr-phase, stage one matrix (hi+lo, 64 KB) into LDS with a linear
// uint4 copy (image is pre-swizzled), inner loop reads ds_read_b128.
__global__ __launch_bounds__(256) void k_gemm(const uint16_t* __restrict__ A1h,
                                              const uint16_t* __restrict__ A1l,
                                              const uint16_t* __restrict__ A2h,
                                              const uint16_t* __restrict__ A2l,
                                              const uint16_t* __restrict__ wl,
                                              const uint16_t* __restrict__ wr,
                                              const float* __restrict__ bias,
                                              uint16_t* __restrict__ outh,
                                              uint16_t* __restrict__ outl) {
    __shared__ __align__(16) uint16_t ldsW[32768];   // 64 KB: one matrix hi+lo
    int tid = threadIdx.x;
    int lane = tid & 63, wv = tid >> 6;
    int li = lane & 15, g4 = lane >> 4;
    int mrow = blockIdx.x * 128 + wv * 32 + li;
    int r0 = min(mrow, N_NODES - 1);
    int r1 = min(mrow + 16, N_NODES - 1);

    f32x4 acc[2][8];
#pragma unroll
    for (int m = 0; m < 2; ++m)
#pragma unroll
        for (int t = 0; t < 8; ++t) acc[m][t] = (f32x4){0.f, 0.f, 0.f, 0.f};

#pragma unroll
    for (int arr = 0; arr < 2; ++arr) {
        // stage this arr's weight image (linear copy; swizzle pre-applied)
        {
            const uint4* g = (const uint4*)(arr ? wr : wl);
            uint4* l = (uint4*)ldsW;
#pragma unroll
            for (int j2 = 0; j2 < 32; ++j2)
                l[j2 * 256 + tid] = g[j2 * 256 + tid];
        }
        __syncthreads();

        const uint16_t* Ah = arr ? A2h : A1h;
        const uint16_t* Al = arr ? A2l : A1l;
#pragma unroll
        for (int s = 0; s < 4; ++s) {
            int ko = s * 32 + g4 * 8;
            short8 a0h = *(const short8*)&Ah[(size_t)r0 * 128 + ko];
            short8 a0l = *(const short8*)&Al[(size_t)r0 * 128 + ko];
            short8 a1h = *(const short8*)&Ah[(size_t)r1 * 128 + ko];
            short8 a1l = *(const short8*)&Al[(size_t)r1 * 128 + ko];
#pragma unroll
            for (int t = 0; t < 8; ++t) {
                int off = (t * 16 + li) * 128 + (((s * 4 + g4) ^ li) << 3);
                short8 bh = *(const short8*)&ldsW[off];
                short8 bl = *(const short8*)&ldsW[off + 16384];
                acc[0][t] = __builtin_amdgcn_mfma_f32_16x16x32_bf16(a0h, bh, acc[0][t], 0, 0, 0);
                acc[0][t] = __builtin_amdgcn_mfma_f32_16x16x32_bf16(a0l, bh, acc[0][t], 0, 0, 0);
                acc[0][t] = __builtin_amdgcn_mfma_f32_16x16x32_bf16(a0h, bl, acc[0][t], 0, 0, 0);
                acc[1][t] = __builtin_amdgcn_mfma_f32_16x16x32_bf16(a1h, bh, acc[1][t], 0, 0, 0);
                acc[1][t] = __builtin_amdgcn_mfma_f32_16x16x32_bf16(a1l, bh, acc[1][t], 0, 0, 0);
                acc[1][t] = __builtin_amdgcn_mfma_f32_16x16x32_bf16(a1h, bl, acc[1][t], 0, 0, 0);
            }
        }
        if (arr == 0) __syncthreads();   // drain reads before restaging
    }
    // epilogue: bias + relu, split hi/lo.  D layout: col=lane&15, row=(lane>>4)*4+rr
    int rowbase = blockIdx.x * 128 + wv * 32 + g4 * 4;
#pragma unroll
    for (int t = 0; t < 8; ++t) {
        int col = t * 16 + li;
        float bv = bias[col];
#pragma unroll
        for (int m = 0; m < 2; ++m) {
#pragma unroll
            for (int rr = 0; rr < 4; ++rr) {
                int row = rowbase + m * 16 + rr;
                if (row < N_NODES) {
                    float v = fmaxf(acc[m][t][rr] + bv, 0.f);
                    uint16_t h = f2bf(v);
                    outh[(size_t)row * 128 + col] = h;
                    outl[(size_t)row * 128 + col] = f2bf(v - bf2f(h));
                }
            }
        }
    }
}

// -------- layer 2 GEMM fused with L2-normalize + log_softmax, out f32[N][47]
__global__ __launch_bounds__(256) void k_gemm2(const uint16_t* __restrict__ A1h,
                                               const uint16_t* __restrict__ A1l,
                                               const uint16_t* __restrict__ A2h,
                                               const uint16_t* __restrict__ A2l,
                                               const uint16_t* __restrict__ wl,
                                               const uint16_t* __restrict__ wr,
                                               const float* __restrict__ bias,
                                               float* __restrict__ out) {
    int tid = threadIdx.x;
    int lane = tid & 63, wv = tid >> 6;
    int li = lane & 15, g4 = lane >> 4;
    int mrow = blockIdx.x * 64 + wv * 16 + li;
    int r = min(mrow, N_NODES - 1);

    f32x4 acc[3];
#pragma unroll
    for (int t = 0; t < 3; ++t) acc[t] = (f32x4){0.f, 0.f, 0.f, 0.f};

#pragma unroll
    for (int arr = 0; arr < 2; ++arr) {
        const uint16_t* Ah = arr ? A2h : A1h;
        const uint16_t* Al = arr ? A2l : A1l;
        const uint16_t* W  = arr ? wr : wl;
#pragma unroll
        for (int s = 0; s < 4; ++s) {
            int ko = s * 32 + g4 * 8;
            short8 ah = *(const short8*)&Ah[(size_t)r * 128 + ko];
            short8 al = *(const short8*)&Al[(size_t)r * 128 + ko];
#pragma unroll
            for (int t = 0; t < 3; ++t) {
                const uint16_t* p = &W[(t * 16 + li) * 128 + ko];
                short8 bh = *(const short8*)p;
                short8 bl = *(const short8*)(p + 6144);
                acc[t] = __builtin_amdgcn_mfma_f32_16x16x32_bf16(ah, bh, acc[t], 0, 0, 0);
                acc[t] = __builtin_amdgcn_mfma_f32_16x16x32_bf16(al, bh, acc[t], 0, 0, 0);
                acc[t] = __builtin_amdgcn_mfma_f32_16x16x32_bf16(ah, bl, acc[t], 0, 0, 0);
            }
        }
    }

    float b0 = bias[li];
    float b1 = bias[16 + li];
    bool v2ok = (li < 15);
    float b2 = v2ok ? bias[32 + li] : 0.f;

    int rowbase = blockIdx.x * 64 + wv * 16 + g4 * 4;
#pragma unroll
    for (int rr = 0; rr < 4; ++rr) {
        int row = rowbase + rr;
        float v0 = acc[0][rr] + b0;
        float v1 = acc[1][rr] + b1;
        float v2 = v2ok ? (acc[2][rr] + b2) : 0.f;
        float ss = v0 * v0 + v1 * v1 + v2 * v2;
        ss += __shfl_xor(ss, 1);
        ss += __shfl_xor(ss, 2);
        ss += __shfl_xor(ss, 4);
        ss += __shfl_xor(ss, 8);
        float inv = 1.f / fmaxf(sqrtf(ss), 1e-12f);
        v0 *= inv; v1 *= inv; v2 *= inv;
        float mx = fmaxf(v0, v1);
        if (v2ok) mx = fmaxf(mx, v2);
        mx = fmaxf(mx, __shfl_xor(mx, 1));
        mx = fmaxf(mx, __shfl_xor(mx, 2));
        mx = fmaxf(mx, __shfl_xor(mx, 4));
        mx = fmaxf(mx, __shfl_xor(mx, 8));
        float se = expf(v0 - mx) + expf(v1 - mx) + (v2ok ? expf(v2 - mx) : 0.f);
        se += __shfl_xor(se, 1);
        se += __shfl_xor(se, 2);
        se += __shfl_xor(se, 4);
        se += __shfl_xor(se, 8);
        float lse = logf(se);
        if (row < N_NODES) {
            size_t ob = (size_t)row * NCLS;
            out[ob + li]      = v0 - mx - lse;
            out[ob + 16 + li] = v1 - mx - lse;
            if (v2ok) out[ob + 32 + li] = v2 - mx - lse;
        }
    }
}

// ---------------------------------------------------------------------------
extern "C" void kernel_launch(void* const* d_in, const int* in_sizes, int n_in,
                              void* d_out, int out_size, void* d_ws, size_t ws_size,
                              hipStream_t stream) {
    const float* x   = (const float*)d_in[0];
    const int*   ei  = (const int*)d_in[1];
    const float* Wl0 = (const float*)d_in[2];
    const float* bl0 = (const float*)d_in[3];
    const float* Wr0 = (const float*)d_in[4];
    const float* Wl1 = (const float*)d_in[5];
    const float* bl1 = (const float*)d_in[6];
    const float* Wr1 = (const float*)d_in[7];
    const float* Wl2 = (const float*)d_in[8];
    const float* bl2 = (const float*)d_in[9];
    const float* Wr2 = (const float*)d_in[10];
    float* out = (float*)d_out;

    char* ws = (char*)d_ws;
    size_t cur = 0;
    auto alloc = [&](size_t bytes) {
        char* p = ws + cur;
        cur += (bytes + 255) & ~(size_t)255;
        return p;
    };
    const size_t MATB = (size_t)N_NODES * 128 * 2;   // bf16 matrix bytes
    int*      deg       = (int*)alloc(N_NODES * 4);
    int*      row_start = (int*)alloc(N_NODES * 4);
    int*      fill      = (int*)alloc(N_NODES * 4);
    float*    inv_deg   = (float*)alloc(N_NODES * 4);
    int*      partial   = (int*)alloc(SCAN_BLOCKS * 4);
    int*      src       = (int*)alloc(N_EDGES * 4);
    int*      dst       = (int*)alloc(N_EDGES * 4);
    int*      elist     = (int*)alloc(N_EDGES * 4);
    uint16_t* wimg      = (uint16_t*)alloc(155648 * 2);
    uint16_t* xh        = (uint16_t*)alloc(MATB);
    uint16_t* xl        = (uint16_t*)alloc(MATB);
    uint16_t* Ah        = (uint16_t*)alloc(MATB);
    uint16_t* Al        = (uint16_t*)alloc(MATB);
    uint16_t* Bh        = (uint16_t*)alloc(MATB);
    uint16_t* Bl        = (uint16_t*)alloc(MATB);
    uint16_t* Ch        = (uint16_t*)alloc(MATB);
    uint16_t* Cl        = (uint16_t*)alloc(MATB);

    hipMemsetAsync(deg, 0, N_NODES * 4, stream);
    k_prepw<<<384, 256, 0, stream>>>(Wl0, Wr0, Wl1, Wr1, Wl2, Wr2, wimg);
    k_split<<<(N_NODES * 128 / 4) / 256, 256, 0, stream>>>((const float4*)x,
                                                           (ushort4*)xh, (ushort4*)xl);

    int egrid = (N_EDGES + 255) / 256;
    k_cvt_idx<<<egrid, 256, 0, stream>>>(ei, src, dst, deg);
    k_scan1<<<SCAN_BLOCKS, SCAN_TPB, 0, stream>>>(deg, partial);
    k_scan2<<<1, 128, 0, stream>>>(partial);
    k_scan3<<<SCAN_BLOCKS, SCAN_TPB, 0, stream>>>(deg, partial, row_start, fill, inv_deg);
    k_fill<<<egrid, 256, 0, stream>>>(src, dst, fill, elist);

    int agrid = (N_NODES + 3) / 4;           // 12500 (1 wave/node)
    int ggrid = (N_NODES + 127) / 128;       // 391
    int g2grid = (N_NODES + 63) / 64;        // 782

    // layer 0
    k_agg<<<agrid, 256, 0, stream>>>(xh, row_start, deg, inv_deg, elist, Ah, Al);
    k_gemm<<<ggrid, 256, 0, stream>>>(Ah, Al, xh, xl, wimg, wimg + 32768, bl0, Bh, Bl);
    // layer 1
    k_agg<<<agrid, 256, 0, stream>>>(Bh, row_start, deg, inv_deg, elist, Ah, Al);
    k_gemm<<<ggrid, 256, 0, stream>>>(Ah, Al, Bh, Bl, wimg + 65536, wimg + 98304, bl1, Ch, Cl);
    // layer 2 (fused normalize + log_softmax)
    k_agg<<<agrid, 256, 0, stream>>>(Ch, row_start, deg, inv_deg, elist, Ah, Al);
    k_gemm2<<<g2grid, 256, 0, stream>>>(Ah, Al, Ch, Cl, wimg + 131072, wimg + 143360, bl2, out);
}

// Round 11
// 324.386 us; speedup vs baseline: 1.4747x; 1.1289x over previous
//
#include <hip/hip_runtime.h>
#include <stdint.h>

#define N_NODES 50000
#define N_EDGES 600000
#define NCLS    47
#define SCAN_TPB 512
#define SCAN_BLOCKS ((N_NODES + SCAN_TPB - 1) / SCAN_TPB)   // 98

typedef __attribute__((ext_vector_type(8))) short short8;
typedef __attribute__((ext_vector_type(4))) float f32x4;

static __device__ __forceinline__ float bf2f(uint16_t h) {
    union { uint32_t u; float f; } c; c.u = ((uint32_t)h) << 16; return c.f;
}
static __device__ __forceinline__ float bf2fs(short h) { return bf2f((uint16_t)h); }
static __device__ __forceinline__ uint16_t f2bf(float f) {
    union { float f; uint32_t u; } c; c.f = f;
    uint32_t u = c.u;
    return (uint16_t)((u + 0x7fffu + ((u >> 16) & 1u)) >> 16); // RNE
}

// ---------------- split f32 matrix -> bf16 hi + bf16 lo arrays (x only)
__global__ __launch_bounds__(256) void k_split(const float4* __restrict__ x,
                                               ushort4* __restrict__ xh,
                                               ushort4* __restrict__ xl) {
    int i = blockIdx.x * 256 + threadIdx.x;   // 1.6M float4s
    float4 v = x[i];
    ushort4 h, l;
    h.x = f2bf(v.x); l.x = f2bf(v.x - bf2f(h.x));
    h.y = f2bf(v.y); l.y = f2bf(v.y - bf2f(h.y));
    h.z = f2bf(v.z); l.z = f2bf(v.z - bf2f(h.z));
    h.w = f2bf(v.w); l.w = f2bf(v.w - bf2f(h.w));
    xh[i] = h;
    xl[i] = l;
}

// ---------- edge_index canonicalize (int64-or-int32 -> int32) + degree count
__global__ __launch_bounds__(256) void k_cvt_idx(const int* __restrict__ ei,
                                                 int* __restrict__ src,
                                                 int* __restrict__ dst,
                                                 int* __restrict__ deg) {
    __shared__ int is64;
    {
        int lane = threadIdx.x;
        if (lane < 64) {
            int f = ei[2 * lane + 1] | ei[2 * lane + 129]; // 128 hi-words if int64
            unsigned long long m = __ballot(f != 0);
            if (lane == 0) is64 = (m == 0ULL) ? 1 : 0;
        }
        __syncthreads();
    }
    int e = blockIdx.x * 256 + threadIdx.x;
    if (e < N_EDGES) {
        int s, d;
        if (is64) { s = ei[2 * e]; d = ei[2 * (N_EDGES + e)]; }
        else      { s = ei[e];     d = ei[N_EDGES + e]; }
        s = min(max(s, 0), N_NODES - 1);
        d = min(max(d, 0), N_NODES - 1);
        src[e] = s;
        dst[e] = d;
        atomicAdd(&deg[d], 1);
    }
}

// ------------------------------------------- scan stage 1: per-block partials
__global__ __launch_bounds__(SCAN_TPB) void k_scan1(const int* __restrict__ deg,
                                                    int* __restrict__ partial) {
    int t = blockIdx.x * SCAN_TPB + threadIdx.x;
    int v = (t < N_NODES) ? deg[t] : 0;
#pragma unroll
    for (int o = 1; o < 64; o <<= 1) v += __shfl_xor(v, o);
    __shared__ int ws[SCAN_TPB / 64];
    int lane = threadIdx.x & 63, w = threadIdx.x >> 6;
    if (lane == 0) ws[w] = v;
    __syncthreads();
    if (threadIdx.x == 0) {
        int s = 0;
#pragma unroll
        for (int i = 0; i < SCAN_TPB / 64; ++i) s += ws[i];
        partial[blockIdx.x] = s;
    }
}

// ---------------------------- scan stage 2: exclusive scan of 98 partials
__global__ __launch_bounds__(128) void k_scan2(int* __restrict__ partial) {
    __shared__ int sh[128];
    int t = threadIdx.x;
    int v = (t < SCAN_BLOCKS) ? partial[t] : 0;
    sh[t] = v;
    __syncthreads();
    for (int o = 1; o < 128; o <<= 1) {
        int u = (t >= o) ? sh[t - o] : 0;
        __syncthreads();
        sh[t] += u;
        __syncthreads();
    }
    if (t < SCAN_BLOCKS) partial[t] = sh[t] - v; // exclusive
}

// --------------- scan stage 3: block-local exclusive scan + offset, emit CSR
__global__ __launch_bounds__(SCAN_TPB) void k_scan3(const int* __restrict__ deg,
                                                    const int* __restrict__ partial,
                                                    int* __restrict__ row_start,
                                                    int* __restrict__ fill,
                                                    float* __restrict__ inv_deg) {
    int tb = threadIdx.x;
    int t = blockIdx.x * SCAN_TPB + tb;
    int v = (t < N_NODES) ? deg[t] : 0;
    int lane = tb & 63, w = tb >> 6;
    int inc = v;
#pragma unroll
    for (int o = 1; o < 64; o <<= 1) {
        int u = __shfl_up(inc, o);
        if (lane >= o) inc += u;
    }
    __shared__ int wsum[SCAN_TPB / 64];
    if (lane == 63) wsum[w] = inc;
    __syncthreads();
    int woff = 0;
    for (int i = 0; i < w; ++i) woff += wsum[i];
    int excl = partial[blockIdx.x] + woff + (inc - v);
    if (t < N_NODES) {
        row_start[t] = excl;
        fill[t] = excl;
        inv_deg[t] = 1.0f / (float)(v > 0 ? v : 1);
    }
}

// ---------------------------------------------------------------- bucket fill
__global__ __launch_bounds__(256) void k_fill(const int* __restrict__ src,
                                              const int* __restrict__ dst,
                                              int* __restrict__ fill,
                                              int* __restrict__ elist) {
    int e = blockIdx.x * 256 + threadIdx.x;
    if (e < N_EDGES) {
        int pos = atomicAdd(&fill[dst[e]], 1);
        elist[pos] = src[e];
    }
}

// -------- mean aggregation, HI-ONLY input (halves gather traffic), hi/lo out.
// 1 wave/node: 4 edge-groups x 16 lanes, 2-deep unroll, shfl cross-group sum.
__global__ __launch_bounds__(256) void k_agg(const uint16_t* __restrict__ hm_h,
                                             const int* __restrict__ row_start,
                                             const int* __restrict__ degv,
                                             const float* __restrict__ inv_deg,
                                             const int* __restrict__ elist,
                                             uint16_t* __restrict__ agg_h,
                                             uint16_t* __restrict__ agg_l) {
    int lane = threadIdx.x & 63;
    int node = blockIdx.x * 4 + (threadIdx.x >> 6);
    if (node >= N_NODES) return;
    int g = lane >> 4;                      // edge-group 0..3
    int li = lane & 15;
    int j = li * 8;                         // this lane's 8-elem chunk
    int rs = row_start[node];
    int d = degv[node];
    float a[8];
#pragma unroll
    for (int k = 0; k < 8; ++k) a[k] = 0.f;
    int i = g;
    for (; i + 4 < d; i += 8) {             // 2 gathers in flight per lane
        int s0 = elist[rs + i];
        int s1 = elist[rs + i + 4];
        short8 w0 = *(const short8*)&hm_h[(size_t)s0 * 128 + j];
        short8 w1 = *(const short8*)&hm_h[(size_t)s1 * 128 + j];
#pragma unroll
        for (int k = 0; k < 8; ++k) a[k] += bf2fs(w0[k]) + bf2fs(w1[k]);
    }
    if (i < d) {
        int s = elist[rs + i];
        short8 w = *(const short8*)&hm_h[(size_t)s * 128 + j];
#pragma unroll
        for (int k = 0; k < 8; ++k) a[k] += bf2fs(w[k]);
    }
    float sc = inv_deg[node];
    short8 oh, ol;
#pragma unroll
    for (int k = 0; k < 8; ++k) {
        float v = a[k];
        v += __shfl_xor(v, 16);
        v += __shfl_xor(v, 32);
        v *= sc;
        uint16_t h = f2bf(v);
        oh[k] = (short)h;
        ol[k] = (short)f2bf(v - bf2f(h));
    }
    if (g == 0)      *(short8*)&agg_h[(size_t)node * 128 + j] = oh;
    else if (g == 1) *(short8*)&agg_l[(size_t)node * 128 + j] = ol;
}

// -------------- weight prep: transpose W[k][col] -> img[col][k], bf16 hi + lo
// Matrices 0-3 (128-col, used by LDS k_gemm) get a bank-conflict swizzle
// baked into the image: chunk (k>>3) XOR'd with (col&15). Staging to LDS is
// then a linear identity copy; ds_read applies the same XOR.
__global__ __launch_bounds__(256) void k_prepw(const float* Wl0, const float* Wr0,
                                               const float* Wl1, const float* Wr1,
                                               const float* Wl2, const float* Wr2,
                                               uint16_t* __restrict__ img) {
    int b = blockIdx.x >> 6;
    int sub = blockIdx.x & 63;
    const float* W; int ncol, npad; uint16_t* o;
    switch (b) {
        case 0: W = Wl0; ncol = 128; npad = 128; o = img;           break;
        case 1: W = Wr0; ncol = 128; npad = 128; o = img + 32768;   break;
        case 2: W = Wl1; ncol = 128; npad = 128; o = img + 65536;   break;
        case 3: W = Wr1; ncol = 128; npad = 128; o = img + 98304;   break;
        case 4: W = Wl2; ncol = 47;  npad = 48;  o = img + 131072;  break;
        default:W = Wr2; ncol = 47;  npad = 48;  o = img + 143360;  break;
    }
    int elems = npad * 128;
    int i = sub * 256 + threadIdx.x;
    if (i < elems) {
        int col = i % npad, k = i / npad;
        float v = (col < ncol) ? W[k * ncol + col] : 0.f;
        uint16_t h = f2bf(v);
        uint16_t l = f2bf(v - bf2f(h));
        int idx;
        if (b < 4) idx = col * 128 + (((k >> 3) ^ (col & 15)) << 3) + (k & 7);
        else       idx = col * 128 + k;
        o[idx] = h;
        o[idx + elems] = l;
    }
}

// ------- GEMM layers 0/1: out(hi/lo) = relu(A1@Wl + A2@Wr + b)
// 512 threads / 8 waves / 16 rows/wave / 128 rows/block (grid 391).
// LDS-resident W (64 KB per arr-phase, pre-swizzled image, linear staging).
// 8 waves -> 12 waves/CU (3/SIMD), 2x round-10 occupancy; acc = 32 VGPR.
__global__ __launch_bounds__(512) void k_gemm(const uint16_t* __restrict__ A1h,
                                              const uint16_t* __restrict__ A1l,
                                              const uint16_t* __restrict__ A2h,
                                              const uint16_t* __restrict__ A2l,
                                              const uint16_t* __restrict__ wl,
                                              const uint16_t* __restrict__ wr,
                                              const float* __restrict__ bias,
                                              uint16_t* __restrict__ outh,
                                              uint16_t* __restrict__ outl) {
    __shared__ __align__(16) uint16_t ldsW[32768];   // 64 KB: one matrix hi+lo
    int tid = threadIdx.x;
    int lane = tid & 63, wv = tid >> 6;              // 8 waves
    int li = lane & 15, g4 = lane >> 4;
    int mrow = blockIdx.x * 128 + wv * 16 + li;
    int r0 = min(mrow, N_NODES - 1);

    f32x4 acc[8];
#pragma unroll
    for (int t = 0; t < 8; ++t) acc[t] = (f32x4){0.f, 0.f, 0.f, 0.f};

#pragma unroll
    for (int arr = 0; arr < 2; ++arr) {
        // stage this arr's weight image (linear copy; swizzle pre-applied)
        {
            const uint4* g = (const uint4*)(arr ? wr : wl);
            uint4* l = (uint4*)ldsW;
#pragma unroll
            for (int j2 = 0; j2 < 8; ++j2)           // 4096 uint4 / 512 thr
                l[j2 * 512 + tid] = g[j2 * 512 + tid];
        }
        __syncthreads();

        const uint16_t* Ah = arr ? A2h : A1h;
        const uint16_t* Al = arr ? A2l : A1l;
#pragma unroll
        for (int s = 0; s < 4; ++s) {
            int ko = s * 32 + g4 * 8;
            short8 a0h = *(const short8*)&Ah[(size_t)r0 * 128 + ko];
            short8 a0l = *(const short8*)&Al[(size_t)r0 * 128 + ko];
#pragma unroll
            for (int t = 0; t < 8; ++t) {
                int off = (t * 16 + li) * 128 + (((s * 4 + g4) ^ li) << 3);
                short8 bh = *(const short8*)&ldsW[off];
                short8 bl = *(const short8*)&ldsW[off + 16384];
                acc[t] = __builtin_amdgcn_mfma_f32_16x16x32_bf16(a0h, bh, acc[t], 0, 0, 0);
                acc[t] = __builtin_amdgcn_mfma_f32_16x16x32_bf16(a0l, bh, acc[t], 0, 0, 0);
                acc[t] = __builtin_amdgcn_mfma_f32_16x16x32_bf16(a0h, bl, acc[t], 0, 0, 0);
            }
        }
        if (arr == 0) __syncthreads();   // drain reads before restaging
    }
    // epilogue: bias + relu, split hi/lo.  D layout: col=lane&15, row=(lane>>4)*4+rr
    int rowbase = blockIdx.x * 128 + wv * 16 + g4 * 4;
#pragma unroll
    for (int t = 0; t < 8; ++t) {
        int col = t * 16 + li;
        float bv = bias[col];
#pragma unroll
        for (int rr = 0; rr < 4; ++rr) {
            int row = rowbase + rr;
            if (row < N_NODES) {
                float v = fmaxf(acc[t][rr] + bv, 0.f);
                uint16_t h = f2bf(v);
                outh[(size_t)row * 128 + col] = h;
                outl[(size_t)row * 128 + col] = f2bf(v - bf2f(h));
            }
        }
    }
}

// -------- layer 2 GEMM fused with L2-normalize + log_softmax, out f32[N][47]
__global__ __launch_bounds__(256) void k_gemm2(const uint16_t* __restrict__ A1h,
                                               const uint16_t* __restrict__ A1l,
                                               const uint16_t* __restrict__ A2h,
                                               const uint16_t* __restrict__ A2l,
                                               const uint16_t* __restrict__ wl,
                                               const uint16_t* __restrict__ wr,
                                               const float* __restrict__ bias,
                                               float* __restrict__ out) {
    int tid = threadIdx.x;
    int lane = tid & 63, wv = tid >> 6;
    int li = lane & 15, g4 = lane >> 4;
    int mrow = blockIdx.x * 64 + wv * 16 + li;
    int r = min(mrow, N_NODES - 1);

    f32x4 acc[3];
#pragma unroll
    for (int t = 0; t < 3; ++t) acc[t] = (f32x4){0.f, 0.f, 0.f, 0.f};

#pragma unroll
    for (int arr = 0; arr < 2; ++arr) {
        const uint16_t* Ah = arr ? A2h : A1h;
        const uint16_t* Al = arr ? A2l : A1l;
        const uint16_t* W  = arr ? wr : wl;
#pragma unroll
        for (int s = 0; s < 4; ++s) {
            int ko = s * 32 + g4 * 8;
            short8 ah = *(const short8*)&Ah[(size_t)r * 128 + ko];
            short8 al = *(const short8*)&Al[(size_t)r * 128 + ko];
#pragma unroll
            for (int t = 0; t < 3; ++t) {
                const uint16_t* p = &W[(t * 16 + li) * 128 + ko];
                short8 bh = *(const short8*)p;
                short8 bl = *(const short8*)(p + 6144);
                acc[t] = __builtin_amdgcn_mfma_f32_16x16x32_bf16(ah, bh, acc[t], 0, 0, 0);
                acc[t] = __builtin_amdgcn_mfma_f32_16x16x32_bf16(al, bh, acc[t], 0, 0, 0);
                acc[t] = __builtin_amdgcn_mfma_f32_16x16x32_bf16(ah, bl, acc[t], 0, 0, 0);
            }
        }
    }

    float b0 = bias[li];
    float b1 = bias[16 + li];
    bool v2ok = (li < 15);
    float b2 = v2ok ? bias[32 + li] : 0.f;

    int rowbase = blockIdx.x * 64 + wv * 16 + g4 * 4;
#pragma unroll
    for (int rr = 0; rr < 4; ++rr) {
        int row = rowbase + rr;
        float v0 = acc[0][rr] + b0;
        float v1 = acc[1][rr] + b1;
        float v2 = v2ok ? (acc[2][rr] + b2) : 0.f;
        float ss = v0 * v0 + v1 * v1 + v2 * v2;
        ss += __shfl_xor(ss, 1);
        ss += __shfl_xor(ss, 2);
        ss += __shfl_xor(ss, 4);
        ss += __shfl_xor(ss, 8);
        float inv = 1.f / fmaxf(sqrtf(ss), 1e-12f);
        v0 *= inv; v1 *= inv; v2 *= inv;
        float mx = fmaxf(v0, v1);
        if (v2ok) mx = fmaxf(mx, v2);
        mx = fmaxf(mx, __shfl_xor(mx, 1));
        mx = fmaxf(mx, __shfl_xor(mx, 2));
        mx = fmaxf(mx, __shfl_xor(mx, 4));
        mx = fmaxf(mx, __shfl_xor(mx, 8));
        float se = expf(v0 - mx) + expf(v1 - mx) + (v2ok ? expf(v2 - mx) : 0.f);
        se += __shfl_xor(se, 1);
        se += __shfl_xor(se, 2);
        se += __shfl_xor(se, 4);
        se += __shfl_xor(se, 8);
        float lse = logf(se);
        if (row < N_NODES) {
            size_t ob = (size_t)row * NCLS;
            out[ob + li]      = v0 - mx - lse;
            out[ob + 16 + li] = v1 - mx - lse;
            if (v2ok) out[ob + 32 + li] = v2 - mx - lse;
        }
    }
}

// ---------------------------------------------------------------------------
extern "C" void kernel_launch(void* const* d_in, const int* in_sizes, int n_in,
                              void* d_out, int out_size, void* d_ws, size_t ws_size,
                              hipStream_t stream) {
    const float* x   = (const float*)d_in[0];
    const int*   ei  = (const int*)d_in[1];
    const float* Wl0 = (const float*)d_in[2];
    const float* bl0 = (const float*)d_in[3];
    const float* Wr0 = (const float*)d_in[4];
    const float* Wl1 = (const float*)d_in[5];
    const float* bl1 = (const float*)d_in[6];
    const float* Wr1 = (const float*)d_in[7];
    const float* Wl2 = (const float*)d_in[8];
    const float* bl2 = (const float*)d_in[9];
    const float* Wr2 = (const float*)d_in[10];
    float* out = (float*)d_out;

    char* ws = (char*)d_ws;
    size_t cur = 0;
    auto alloc = [&](size_t bytes) {
        char* p = ws + cur;
        cur += (bytes + 255) & ~(size_t)255;
        return p;
    };
    const size_t MATB = (size_t)N_NODES * 128 * 2;   // bf16 matrix bytes
    int*      deg       = (int*)alloc(N_NODES * 4);
    int*      row_start = (int*)alloc(N_NODES * 4);
    int*      fill      = (int*)alloc(N_NODES * 4);
    float*    inv_deg   = (float*)alloc(N_NODES * 4);
    int*      partial   = (int*)alloc(SCAN_BLOCKS * 4);
    int*      src       = (int*)alloc(N_EDGES * 4);
    int*      dst       = (int*)alloc(N_EDGES * 4);
    int*      elist     = (int*)alloc(N_EDGES * 4);
    uint16_t* wimg      = (uint16_t*)alloc(155648 * 2);
    uint16_t* xh        = (uint16_t*)alloc(MATB);
    uint16_t* xl        = (uint16_t*)alloc(MATB);
    uint16_t* Ah        = (uint16_t*)alloc(MATB);
    uint16_t* Al        = (uint16_t*)alloc(MATB);
    uint16_t* Bh        = (uint16_t*)alloc(MATB);
    uint16_t* Bl        = (uint16_t*)alloc(MATB);
    uint16_t* Ch        = (uint16_t*)alloc(MATB);
    uint16_t* Cl        = (uint16_t*)alloc(MATB);

    hipMemsetAsync(deg, 0, N_NODES * 4, stream);
    k_prepw<<<384, 256, 0, stream>>>(Wl0, Wr0, Wl1, Wr1, Wl2, Wr2, wimg);
    k_split<<<(N_NODES * 128 / 4) / 256, 256, 0, stream>>>((const float4*)x,
                                                           (ushort4*)xh, (ushort4*)xl);

    int egrid = (N_EDGES + 255) / 256;
    k_cvt_idx<<<egrid, 256, 0, stream>>>(ei, src, dst, deg);
    k_scan1<<<SCAN_BLOCKS, SCAN_TPB, 0, stream>>>(deg, partial);
    k_scan2<<<1, 128, 0, stream>>>(partial);
    k_scan3<<<SCAN_BLOCKS, SCAN_TPB, 0, stream>>>(deg, partial, row_start, fill, inv_deg);
    k_fill<<<egrid, 256, 0, stream>>>(src, dst, fill, elist);

    int agrid = (N_NODES + 3) / 4;           // 12500 (1 wave/node)
    int ggrid = (N_NODES + 127) / 128;       // 391
    int g2grid = (N_NODES + 63) / 64;        // 782

    // layer 0
    k_agg<<<agrid, 256, 0, stream>>>(xh, row_start, deg, inv_deg, elist, Ah, Al);
    k_gemm<<<ggrid, 512, 0, stream>>>(Ah, Al, xh, xl, wimg, wimg + 32768, bl0, Bh, Bl);
    // layer 1
    k_agg<<<agrid, 256, 0, stream>>>(Bh, row_start, deg, inv_deg, elist, Ah, Al);
    k_gemm<<<ggrid, 512, 0, stream>>>(Ah, Al, Bh, Bl, wimg + 65536, wimg + 98304, bl1, Ch, Cl);
    // layer 2 (fused normalize + log_softmax)
    k_agg<<<agrid, 256, 0, stream>>>(Ch, row_start, deg, inv_deg, elist, Ah, Al);
    k_gemm2<<<g2grid, 256, 0, stream>>>(Ah, Al, Ch, Cl, wimg + 131072, wimg + 143360, bl2, out);
}

// Round 12
// 287.635 us; speedup vs baseline: 1.6631x; 1.1278x over previous
//
#include <hip/hip_runtime.h>
#include <stdint.h>

#define N_NODES 50000
#define N_EDGES 600000
#define NCLS    47
#define SCAN_TPB 512
#define SCAN_BLOCKS ((N_NODES + SCAN_TPB - 1) / SCAN_TPB)   // 98

typedef __attribute__((ext_vector_type(8))) short short8;
typedef __attribute__((ext_vector_type(4))) float f32x4;

static __device__ __forceinline__ float bf2f(uint16_t h) {
    union { uint32_t u; float f; } c; c.u = ((uint32_t)h) << 16; return c.f;
}
static __device__ __forceinline__ float bf2fs(short h) { return bf2f((uint16_t)h); }
static __device__ __forceinline__ uint16_t f2bf(float f) {
    union { float f; uint32_t u; } c; c.f = f;
    uint32_t u = c.u;
    return (uint16_t)((u + 0x7fffu + ((u >> 16) & 1u)) >> 16); // RNE
}

// ---------------- f32 matrix -> bf16 (hi only)
__global__ __launch_bounds__(256) void k_split(const float4* __restrict__ x,
                                               ushort4* __restrict__ xh) {
    int i = blockIdx.x * 256 + threadIdx.x;   // 1.6M float4s
    float4 v = x[i];
    ushort4 h;
    h.x = f2bf(v.x);
    h.y = f2bf(v.y);
    h.z = f2bf(v.z);
    h.w = f2bf(v.w);
    xh[i] = h;
}

// ---------- degree count straight from edge_index (int64-or-int32)
__global__ __launch_bounds__(256) void k_deg(const int* __restrict__ ei,
                                             int* __restrict__ deg) {
    __shared__ int is64;
    {
        int lane = threadIdx.x;
        if (lane < 64) {
            int f = ei[2 * lane + 1] | ei[2 * lane + 129]; // 128 hi-words if int64
            unsigned long long m = __ballot(f != 0);
            if (lane == 0) is64 = (m == 0ULL) ? 1 : 0;
        }
        __syncthreads();
    }
    int e = blockIdx.x * 256 + threadIdx.x;
    if (e < N_EDGES) {
        int d = is64 ? ei[2 * (N_EDGES + e)] : ei[N_EDGES + e];
        d = min(max(d, 0), N_NODES - 1);
        atomicAdd(&deg[d], 1);
    }
}

// ------------------------------------------- scan stage 1: per-block partials
__global__ __launch_bounds__(SCAN_TPB) void k_scan1(const int* __restrict__ deg,
                                                    int* __restrict__ partial) {
    int t = blockIdx.x * SCAN_TPB + threadIdx.x;
    int v = (t < N_NODES) ? deg[t] : 0;
#pragma unroll
    for (int o = 1; o < 64; o <<= 1) v += __shfl_xor(v, o);
    __shared__ int ws[SCAN_TPB / 64];
    int lane = threadIdx.x & 63, w = threadIdx.x >> 6;
    if (lane == 0) ws[w] = v;
    __syncthreads();
    if (threadIdx.x == 0) {
        int s = 0;
#pragma unroll
        for (int i = 0; i < SCAN_TPB / 64; ++i) s += ws[i];
        partial[blockIdx.x] = s;
    }
}

// ---------------------------- scan stage 2: exclusive scan of 98 partials
__global__ __launch_bounds__(128) void k_scan2(int* __restrict__ partial) {
    __shared__ int sh[128];
    int t = threadIdx.x;
    int v = (t < SCAN_BLOCKS) ? partial[t] : 0;
    sh[t] = v;
    __syncthreads();
    for (int o = 1; o < 128; o <<= 1) {
        int u = (t >= o) ? sh[t - o] : 0;
        __syncthreads();
        sh[t] += u;
        __syncthreads();
    }
    if (t < SCAN_BLOCKS) partial[t] = sh[t] - v; // exclusive
}

// --------------- scan stage 3: block-local exclusive scan + offset, emit CSR
__global__ __launch_bounds__(SCAN_TPB) void k_scan3(const int* __restrict__ deg,
                                                    const int* __restrict__ partial,
                                                    int* __restrict__ row_start,
                                                    int* __restrict__ fill,
                                                    float* __restrict__ inv_deg) {
    int tb = threadIdx.x;
    int t = blockIdx.x * SCAN_TPB + tb;
    int v = (t < N_NODES) ? deg[t] : 0;
    int lane = tb & 63, w = tb >> 6;
    int inc = v;
#pragma unroll
    for (int o = 1; o < 64; o <<= 1) {
        int u = __shfl_up(inc, o);
        if (lane >= o) inc += u;
    }
    __shared__ int wsum[SCAN_TPB / 64];
    if (lane == 63) wsum[w] = inc;
    __syncthreads();
    int woff = 0;
    for (int i = 0; i < w; ++i) woff += wsum[i];
    int excl = partial[blockIdx.x] + woff + (inc - v);
    if (t < N_NODES) {
        row_start[t] = excl;
        fill[t] = excl;
        inv_deg[t] = 1.0f / (float)(v > 0 ? v : 1);
    }
}

// --------------------------- bucket fill (reads edge_index directly)
__global__ __launch_bounds__(256) void k_fill(const int* __restrict__ ei,
                                              int* __restrict__ fill,
                                              int* __restrict__ elist) {
    __shared__ int is64;
    {
        int lane = threadIdx.x;
        if (lane < 64) {
            int f = ei[2 * lane + 1] | ei[2 * lane + 129];
            unsigned long long m = __ballot(f != 0);
            if (lane == 0) is64 = (m == 0ULL) ? 1 : 0;
        }
        __syncthreads();
    }
    int e = blockIdx.x * 256 + threadIdx.x;
    if (e < N_EDGES) {
        int s, d;
        if (is64) { s = ei[2 * e]; d = ei[2 * (N_EDGES + e)]; }
        else      { s = ei[e];     d = ei[N_EDGES + e]; }
        s = min(max(s, 0), N_NODES - 1);
        d = min(max(d, 0), N_NODES - 1);
        int pos = atomicAdd(&fill[d], 1);
        elist[pos] = s;
    }
}

// -------- mean aggregation, bf16 in, bf16 out.
// 1 wave/node: 4 edge-groups x 16 lanes, 2-deep unroll, shfl cross-group sum.
__global__ __launch_bounds__(256) void k_agg(const uint16_t* __restrict__ hm_h,
                                             const int* __restrict__ row_start,
                                             const int* __restrict__ degv,
                                             const float* __restrict__ inv_deg,
                                             const int* __restrict__ elist,
                                             uint16_t* __restrict__ agg_h) {
    int lane = threadIdx.x & 63;
    int node = blockIdx.x * 4 + (threadIdx.x >> 6);
    if (node >= N_NODES) return;
    int g = lane >> 4;                      // edge-group 0..3
    int li = lane & 15;
    int j = li * 8;                         // this lane's 8-elem chunk
    int rs = row_start[node];
    int d = degv[node];
    float a[8];
#pragma unroll
    for (int k = 0; k < 8; ++k) a[k] = 0.f;
    int i = g;
    for (; i + 4 < d; i += 8) {             // 2 gathers in flight per lane
        int s0 = elist[rs + i];
        int s1 = elist[rs + i + 4];
        short8 w0 = *(const short8*)&hm_h[(size_t)s0 * 128 + j];
        short8 w1 = *(const short8*)&hm_h[(size_t)s1 * 128 + j];
#pragma unroll
        for (int k = 0; k < 8; ++k) a[k] += bf2fs(w0[k]) + bf2fs(w1[k]);
    }
    if (i < d) {
        int s = elist[rs + i];
        short8 w = *(const short8*)&hm_h[(size_t)s * 128 + j];
#pragma unroll
        for (int k = 0; k < 8; ++k) a[k] += bf2fs(w[k]);
    }
    float sc = inv_deg[node];
    short8 oh;
#pragma unroll
    for (int k = 0; k < 8; ++k) {
        float v = a[k];
        v += __shfl_xor(v, 16);
        v += __shfl_xor(v, 32);
        oh[k] = (short)f2bf(v * sc);
    }
    if (g == 0) *(short8*)&agg_h[(size_t)node * 128 + j] = oh;
}

// -------------- weight prep: transpose W[k][col] -> img[col][k], bf16 hi + lo
// ALL matrices get the bank-conflict swizzle baked in: chunk (k>>3) ^ (col&15).
__global__ __launch_bounds__(256) void k_prepw(const float* Wl0, const float* Wr0,
                                               const float* Wl1, const float* Wr1,
                                               const float* Wl2, const float* Wr2,
                                               uint16_t* __restrict__ img) {
    int b = blockIdx.x >> 6;
    int sub = blockIdx.x & 63;
    const float* W; int ncol, npad; uint16_t* o;
    switch (b) {
        case 0: W = Wl0; ncol = 128; npad = 128; o = img;           break;
        case 1: W = Wr0; ncol = 128; npad = 128; o = img + 32768;   break;
        case 2: W = Wl1; ncol = 128; npad = 128; o = img + 65536;   break;
        case 3: W = Wr1; ncol = 128; npad = 128; o = img + 98304;   break;
        case 4: W = Wl2; ncol = 47;  npad = 48;  o = img + 131072;  break;
        default:W = Wr2; ncol = 47;  npad = 48;  o = img + 143360;  break;
    }
    int elems = npad * 128;
    int i = sub * 256 + threadIdx.x;
    if (i < elems) {
        int col = i % npad, k = i / npad;
        float v = (col < ncol) ? W[k * ncol + col] : 0.f;
        uint16_t h = f2bf(v);
        uint16_t l = f2bf(v - bf2f(h));
        int idx = col * 128 + (((k >> 3) ^ (col & 15)) << 3) + (k & 7);
        o[idx] = h;
        o[idx + elems] = l;
    }
}

// ------- GEMM layers 0/1: out = relu(A1@Wl + A2@Wr + b), bf16 A, hi/lo W
// 512 threads / 8 waves / 16 rows/wave / 128 rows/block (grid 391).
// LDS-resident W (64 KB per arr-phase, pre-swizzled image, linear staging).
__global__ __launch_bounds__(512) void k_gemm(const uint16_t* __restrict__ A1h,
                                              const uint16_t* __restrict__ A2h,
                                              const uint16_t* __restrict__ wl,
                                              const uint16_t* __restrict__ wr,
                                              const float* __restrict__ bias,
                                              uint16_t* __restrict__ outh) {
    __shared__ __align__(16) uint16_t ldsW[32768];   // 64 KB: one matrix hi+lo
    int tid = threadIdx.x;
    int lane = tid & 63, wv = tid >> 6;              // 8 waves
    int li = lane & 15, g4 = lane >> 4;
    int mrow = blockIdx.x * 128 + wv * 16 + li;
    int r0 = min(mrow, N_NODES - 1);

    f32x4 acc[8];
#pragma unroll
    for (int t = 0; t < 8; ++t) acc[t] = (f32x4){0.f, 0.f, 0.f, 0.f};

#pragma unroll
    for (int arr = 0; arr < 2; ++arr) {
        // stage this arr's weight image (linear copy; swizzle pre-applied)
        {
            const uint4* g = (const uint4*)(arr ? wr : wl);
            uint4* l = (uint4*)ldsW;
#pragma unroll
            for (int j2 = 0; j2 < 8; ++j2)           // 4096 uint4 / 512 thr
                l[j2 * 512 + tid] = g[j2 * 512 + tid];
        }
        __syncthreads();

        const uint16_t* Ah = arr ? A2h : A1h;
#pragma unroll
        for (int s = 0; s < 4; ++s) {
            int ko = s * 32 + g4 * 8;
            short8 a0h = *(const short8*)&Ah[(size_t)r0 * 128 + ko];
#pragma unroll
            for (int t = 0; t < 8; ++t) {
                int off = (t * 16 + li) * 128 + (((s * 4 + g4) ^ li) << 3);
                short8 bh = *(const short8*)&ldsW[off];
                short8 bl = *(const short8*)&ldsW[off + 16384];
                acc[t] = __builtin_amdgcn_mfma_f32_16x16x32_bf16(a0h, bh, acc[t], 0, 0, 0);
                acc[t] = __builtin_amdgcn_mfma_f32_16x16x32_bf16(a0h, bl, acc[t], 0, 0, 0);
            }
        }
        if (arr == 0) __syncthreads();   // drain reads before restaging
    }
    // epilogue: bias + relu, bf16 store.  D layout: col=lane&15, row=(lane>>4)*4+rr
    int rowbase = blockIdx.x * 128 + wv * 16 + g4 * 4;
#pragma unroll
    for (int t = 0; t < 8; ++t) {
        int col = t * 16 + li;
        float bv = bias[col];
#pragma unroll
        for (int rr = 0; rr < 4; ++rr) {
            int row = rowbase + rr;
            if (row < N_NODES)
                outh[(size_t)row * 128 + col] = f2bf(fmaxf(acc[t][rr] + bv, 0.f));
        }
    }
}

// -------- layer 2 GEMM fused with L2-normalize + log_softmax, out f32[N][47]
// 512 threads / 8 waves / 16 rows/wave / 128 rows/block (grid 391).
// Both W2 images (48 KB) LDS-staged once; bf16 A, hi/lo W.
__global__ __launch_bounds__(512) void k_gemm2(const uint16_t* __restrict__ A1h,
                                               const uint16_t* __restrict__ A2h,
                                               const uint16_t* __restrict__ w2,
                                               const float* __restrict__ bias,
                                               float* __restrict__ out) {
    __shared__ __align__(16) uint16_t ldsW[24576];   // 48 KB: wl2+wr2, hi+lo
    int tid = threadIdx.x;
    int lane = tid & 63, wv = tid >> 6;
    int li = lane & 15, g4 = lane >> 4;
    int mrow = blockIdx.x * 128 + wv * 16 + li;
    int r = min(mrow, N_NODES - 1);

    {   // stage both layer-2 images (contiguous 24576 u16 = 6144 uint4)
        const uint4* g = (const uint4*)w2;
        uint4* l = (uint4*)ldsW;
#pragma unroll
        for (int j2 = 0; j2 < 12; ++j2)
            l[j2 * 512 + tid] = g[j2 * 512 + tid];
    }
    __syncthreads();

    f32x4 acc[3];
#pragma unroll
    for (int t = 0; t < 3; ++t) acc[t] = (f32x4){0.f, 0.f, 0.f, 0.f};

#pragma unroll
    for (int arr = 0; arr < 2; ++arr) {
        const uint16_t* Ah = arr ? A2h : A1h;
        const uint16_t* WL = &ldsW[arr * 12288];
#pragma unroll
        for (int s = 0; s < 4; ++s) {
            int ko = s * 32 + g4 * 8;
            short8 ah = *(const short8*)&Ah[(size_t)r * 128 + ko];
#pragma unroll
            for (int t = 0; t < 3; ++t) {
                int off = (t * 16 + li) * 128 + (((s * 4 + g4) ^ li) << 3);
                short8 bh = *(const short8*)&WL[off];
                short8 bl = *(const short8*)&WL[off + 6144];
                acc[t] = __builtin_amdgcn_mfma_f32_16x16x32_bf16(ah, bh, acc[t], 0, 0, 0);
                acc[t] = __builtin_amdgcn_mfma_f32_16x16x32_bf16(ah, bl, acc[t], 0, 0, 0);
            }
        }
    }

    float b0 = bias[li];
    float b1 = bias[16 + li];
    bool v2ok = (li < 15);
    float b2 = v2ok ? bias[32 + li] : 0.f;

    int rowbase = blockIdx.x * 128 + wv * 16 + g4 * 4;
#pragma unroll
    for (int rr = 0; rr < 4; ++rr) {
        int row = rowbase + rr;
        float v0 = acc[0][rr] + b0;
        float v1 = acc[1][rr] + b1;
        float v2 = v2ok ? (acc[2][rr] + b2) : 0.f;
        float ss = v0 * v0 + v1 * v1 + v2 * v2;
        ss += __shfl_xor(ss, 1);
        ss += __shfl_xor(ss, 2);
        ss += __shfl_xor(ss, 4);
        ss += __shfl_xor(ss, 8);
        float inv = 1.f / fmaxf(sqrtf(ss), 1e-12f);
        v0 *= inv; v1 *= inv; v2 *= inv;
        float mx = fmaxf(v0, v1);
        if (v2ok) mx = fmaxf(mx, v2);
        mx = fmaxf(mx, __shfl_xor(mx, 1));
        mx = fmaxf(mx, __shfl_xor(mx, 2));
        mx = fmaxf(mx, __shfl_xor(mx, 4));
        mx = fmaxf(mx, __shfl_xor(mx, 8));
        float se = expf(v0 - mx) + expf(v1 - mx) + (v2ok ? expf(v2 - mx) : 0.f);
        se += __shfl_xor(se, 1);
        se += __shfl_xor(se, 2);
        se += __shfl_xor(se, 4);
        se += __shfl_xor(se, 8);
        float lse = logf(se);
        if (row < N_NODES) {
            size_t ob = (size_t)row * NCLS;
            out[ob + li]      = v0 - mx - lse;
            out[ob + 16 + li] = v1 - mx - lse;
            if (v2ok) out[ob + 32 + li] = v2 - mx - lse;
        }
    }
}

// ---------------------------------------------------------------------------
extern "C" void kernel_launch(void* const* d_in, const int* in_sizes, int n_in,
                              void* d_out, int out_size, void* d_ws, size_t ws_size,
                              hipStream_t stream) {
    const float* x   = (const float*)d_in[0];
    const int*   ei  = (const int*)d_in[1];
    const float* Wl0 = (const float*)d_in[2];
    const float* bl0 = (const float*)d_in[3];
    const float* Wr0 = (const float*)d_in[4];
    const float* Wl1 = (const float*)d_in[5];
    const float* bl1 = (const float*)d_in[6];
    const float* Wr1 = (const float*)d_in[7];
    const float* Wl2 = (const float*)d_in[8];
    const float* bl2 = (const float*)d_in[9];
    const float* Wr2 = (const float*)d_in[10];
    float* out = (float*)d_out;

    char* ws = (char*)d_ws;
    size_t cur = 0;
    auto alloc = [&](size_t bytes) {
        char* p = ws + cur;
        cur += (bytes + 255) & ~(size_t)255;
        return p;
    };
    const size_t MATB = (size_t)N_NODES * 128 * 2;   // bf16 matrix bytes
    int*      deg       = (int*)alloc(N_NODES * 4);
    int*      row_start = (int*)alloc(N_NODES * 4);
    int*      fill      = (int*)alloc(N_NODES * 4);
    float*    inv_deg   = (float*)alloc(N_NODES * 4);
    int*      partial   = (int*)alloc(SCAN_BLOCKS * 4);
    int*      elist     = (int*)alloc(N_EDGES * 4);
    uint16_t* wimg      = (uint16_t*)alloc(155648 * 2);
    uint16_t* xh        = (uint16_t*)alloc(MATB);
    uint16_t* Ah        = (uint16_t*)alloc(MATB);
    uint16_t* Bh        = (uint16_t*)alloc(MATB);
    uint16_t* Ch        = (uint16_t*)alloc(MATB);

    hipMemsetAsync(deg, 0, N_NODES * 4, stream);
    k_prepw<<<384, 256, 0, stream>>>(Wl0, Wr0, Wl1, Wr1, Wl2, Wr2, wimg);
    k_split<<<(N_NODES * 128 / 4) / 256, 256, 0, stream>>>((const float4*)x, (ushort4*)xh);

    int egrid = (N_EDGES + 255) / 256;
    k_deg<<<egrid, 256, 0, stream>>>(ei, deg);
    k_scan1<<<SCAN_BLOCKS, SCAN_TPB, 0, stream>>>(deg, partial);
    k_scan2<<<1, 128, 0, stream>>>(partial);
    k_scan3<<<SCAN_BLOCKS, SCAN_TPB, 0, stream>>>(deg, partial, row_start, fill, inv_deg);
    k_fill<<<egrid, 256, 0, stream>>>(ei, fill, elist);

    int agrid = (N_NODES + 3) / 4;           // 12500 (1 wave/node)
    int ggrid = (N_NODES + 127) / 128;       // 391

    // layer 0
    k_agg<<<agrid, 256, 0, stream>>>(xh, row_start, deg, inv_deg, elist, Ah);
    k_gemm<<<ggrid, 512, 0, stream>>>(Ah, xh, wimg, wimg + 32768, bl0, Bh);
    // layer 1
    k_agg<<<agrid, 256, 0, stream>>>(Bh, row_start, deg, inv_deg, elist, Ah);
    k_gemm<<<ggrid, 512, 0, stream>>>(Ah, Bh, wimg + 65536, wimg + 98304, bl1, Ch);
    // layer 2 (fused normalize + log_softmax)
    k_agg<<<agrid, 256, 0, stream>>>(Ch, row_start, deg, inv_deg, elist, Ah);
    k_gemm2<<<ggrid, 512, 0, stream>>>(Ah, Ch, wimg + 131072, bl2, out);
}